// Round 3
// baseline (2498.454 us; speedup 1.0000x reference)
//
#include <hip/hip_runtime.h>
#include <math.h>

// Problem constants (shapes fixed by reference setup_inputs)
constexpr int Bn = 4;
constexpr int Cc = 512;
constexpr int CQ = 128;
constexpr int Hh = 128, Ww = 128;
constexpr int Nn = Hh * Ww;        // 16384
constexpr int NPATCH = 64;         // B * 4 * 4
constexpr float EPSf = 1e-10f;

// ---------------------------------------------------------------------------
// Fused QKV 1x1-conv GEMM. Computes transposed (channel-last) outputs:
//   q_t[(b,n)][cq], k_t[(b,n)][cq], v_t[(b,n)][c]
// A-tile = X (n-dim rows), B-tile = W (c-dim cols). 128x128 tile, 8x8/thread.
// CL=false: x is standard [B][C][N]; CL=true: x is channel-last [(b,n)][C].
// ---------------------------------------------------------------------------
template<bool CL>
__global__ __launch_bounds__(256) void qkv_gemm(
    const float* __restrict__ xsrc,
    const float* __restrict__ wq, const float* __restrict__ bq,
    const float* __restrict__ wk, const float* __restrict__ bk,
    const float* __restrict__ wv, const float* __restrict__ bv,
    float* __restrict__ q_t, float* __restrict__ k_t, float* __restrict__ v_t)
{
    __shared__ float As[16][132];
    __shared__ float Bs[16][132];
    const int t  = threadIdx.x;
    const int ty = t >> 4, tx = t & 15;
    const int n0 = blockIdx.x * 128;
    const int r0 = blockIdx.y * 128;   // 0,128,256,384,512,640
    const int b  = blockIdx.z;

    const float* Wp; const float* bias; float* outp; int oc0, OC;
    if (r0 == 0)        { Wp = wq;                        bias = bq;             outp = q_t; oc0 = 0;      OC = CQ; }
    else if (r0 == 128) { Wp = wk;                        bias = bk;             outp = k_t; oc0 = 0;      OC = CQ; }
    else                { Wp = wv + (size_t)(r0-256)*Cc;  bias = bv + (r0-256);  outp = v_t; oc0 = r0-256; OC = Cc; }

    float acc[8][8];
    #pragma unroll
    for (int i = 0; i < 8; i++)
        #pragma unroll
        for (int j = 0; j < 8; j++) acc[i][j] = 0.f;

    for (int k0 = 0; k0 < Cc; k0 += 16) {
        if (!CL) {
            // As[kk][n] = x[b][k0+kk][n0+n] : contiguous along n
            const int kk = t >> 4;
            const int cg = (t & 15) * 8;
            const float* src = xsrc + ((size_t)b*Cc + k0 + kk)*Nn + n0 + cg;
            float4 v0 = *(const float4*)src;
            float4 v1 = *(const float4*)(src + 4);
            *(float4*)&As[kk][cg]     = v0;
            *(float4*)&As[kk][cg + 4] = v1;
        } else {
            // As[kk][n] = x1[(b,n0+n)][k0+kk] : transpose-stage
            const int nr  = t >> 1;
            const int kk0 = (t & 1) * 8;
            const float* src = xsrc + ((size_t)b*Nn + n0 + nr)*Cc + k0 + kk0;
            float4 v0 = *(const float4*)src;
            float4 v1 = *(const float4*)(src + 4);
            As[kk0+0][nr]=v0.x; As[kk0+1][nr]=v0.y; As[kk0+2][nr]=v0.z; As[kk0+3][nr]=v0.w;
            As[kk0+4][nr]=v1.x; As[kk0+5][nr]=v1.y; As[kk0+6][nr]=v1.z; As[kk0+7][nr]=v1.w;
        }
        {
            // Bs[kk][c] = W[c][k0+kk] : transpose-stage
            const int c   = t >> 1;
            const int kk0 = (t & 1) * 8;
            const float* src = Wp + (size_t)c*Cc + k0 + kk0;
            float4 v0 = *(const float4*)src;
            float4 v1 = *(const float4*)(src + 4);
            Bs[kk0+0][c]=v0.x; Bs[kk0+1][c]=v0.y; Bs[kk0+2][c]=v0.z; Bs[kk0+3][c]=v0.w;
            Bs[kk0+4][c]=v1.x; Bs[kk0+5][c]=v1.y; Bs[kk0+6][c]=v1.z; Bs[kk0+7][c]=v1.w;
        }
        __syncthreads();
        #pragma unroll
        for (int kk = 0; kk < 16; kk++) {
            float4 alo = *(const float4*)&As[kk][ty*4];
            float4 ahi = *(const float4*)&As[kk][64 + ty*4];
            float4 blo = *(const float4*)&Bs[kk][tx*4];
            float4 bhi = *(const float4*)&Bs[kk][64 + tx*4];
            float av[8] = {alo.x,alo.y,alo.z,alo.w,ahi.x,ahi.y,ahi.z,ahi.w};
            float bw[8] = {blo.x,blo.y,blo.z,blo.w,bhi.x,bhi.y,bhi.z,bhi.w};
            #pragma unroll
            for (int i = 0; i < 8; i++)
                #pragma unroll
                for (int j = 0; j < 8; j++)
                    acc[i][j] = fmaf(av[i], bw[j], acc[i][j]);
        }
        __syncthreads();
    }

    float bl[8];
    {
        float4 b0 = *(const float4*)&bias[tx*4];
        float4 b1 = *(const float4*)&bias[64 + tx*4];
        bl[0]=b0.x; bl[1]=b0.y; bl[2]=b0.z; bl[3]=b0.w;
        bl[4]=b1.x; bl[5]=b1.y; bl[6]=b1.z; bl[7]=b1.w;
    }
    #pragma unroll
    for (int half = 0; half < 2; half++)
        #pragma unroll
        for (int ii = 0; ii < 4; ii++) {
            const int nrow = half*64 + ty*4 + ii;
            float* op = outp + ((size_t)b*Nn + n0 + nrow)*OC + oc0;
            const int ai = half*4 + ii;
            float4 o0, o1;
            o0.x = acc[ai][0] + bl[0]; o0.y = acc[ai][1] + bl[1];
            o0.z = acc[ai][2] + bl[2]; o0.w = acc[ai][3] + bl[3];
            o1.x = acc[ai][4] + bl[4]; o1.y = acc[ai][5] + bl[5];
            o1.z = acc[ai][6] + bl[6]; o1.w = acc[ai][7] + bl[7];
            *(float4*)&op[tx*4]      = o0;
            *(float4*)&op[64 + tx*4] = o1;
        }
}

// ---------------------------------------------------------------------------
// Per-position channel norms of q,k (channel-last layout -> per-thread rows)
// ---------------------------------------------------------------------------
__global__ __launch_bounds__(256) void qk_norms(
    const float* __restrict__ q_t, const float* __restrict__ k_t,
    float* __restrict__ nq, float* __restrict__ nk)
{
    const int pos = blockIdx.x * 256 + threadIdx.x;  // < B*N
    const float* qp = q_t + (size_t)pos * CQ;
    const float* kp = k_t + (size_t)pos * CQ;
    float sq = 0.f, sk = 0.f;
    #pragma unroll
    for (int c = 0; c < CQ; c += 4) {
        float4 a = *(const float4*)&qp[c];
        float4 bb = *(const float4*)&kp[c];
        sq += a.x*a.x + a.y*a.y + a.z*a.z + a.w*a.w;
        sk += bb.x*bb.x + bb.y*bb.y + bb.z*bb.z + bb.w*bb.w;
    }
    nq[pos] = sqrtf(sq) + EPSf;
    nk[pos] = sqrtf(sk) + EPSf;
}

// ---------------------------------------------------------------------------
// energy_H: per (patch, column w): E[h][g] = qn(h,w) . kn(g,w)
// writes att[p][h][w][0..31]
// ---------------------------------------------------------------------------
__global__ __launch_bounds__(256) void energy_H(
    const float* __restrict__ q_t, const float* __restrict__ k_t,
    const float* __restrict__ nq, const float* __restrict__ nk,
    float* __restrict__ att)
{
    __shared__ float Qs[32][129], Ks[32][129];
    __shared__ float nqs[32], nks[32];
    const int w = blockIdx.x, p = blockIdx.y;
    const int b = p >> 4, pi = (p >> 2) & 3, pj = p & 3;
    const int gw = pj*32 + w;
    const int t = threadIdx.x;
    {
        const int h  = t >> 3;
        const int c0 = (t & 7) * 16;
        const size_t base = ((size_t)b*Nn + (size_t)(pi*32 + h)*Ww + gw) * CQ + c0;
        #pragma unroll
        for (int u = 0; u < 16; u += 4) {
            float4 qa = *(const float4*)&q_t[base + u];
            float4 ka = *(const float4*)&k_t[base + u];
            Qs[h][c0+u]=qa.x; Qs[h][c0+u+1]=qa.y; Qs[h][c0+u+2]=qa.z; Qs[h][c0+u+3]=qa.w;
            Ks[h][c0+u]=ka.x; Ks[h][c0+u+1]=ka.y; Ks[h][c0+u+2]=ka.z; Ks[h][c0+u+3]=ka.w;
        }
    }
    if (t < 32) {
        const size_t pp = (size_t)b*Nn + (size_t)(pi*32 + t)*Ww + gw;
        nqs[t] = nq[pp]; nks[t] = nk[pp];
    }
    __syncthreads();
    const int h0 = (t & 15) * 2, g0 = (t >> 4) * 2;
    float a00=0,a01=0,a10=0,a11=0;
    #pragma unroll 4
    for (int c = 0; c < CQ; c++) {
        float q0 = Qs[h0][c], q1 = Qs[h0+1][c];
        float k0 = Ks[g0][c], k1 = Ks[g0+1][c];
        a00 = fmaf(q0,k0,a00); a01 = fmaf(q0,k1,a01);
        a10 = fmaf(q1,k0,a10); a11 = fmaf(q1,k1,a11);
    }
    const size_t ab = (((size_t)p*32 + h0)*32 + w)*64;
    att[ab + g0]            = a00 / (nqs[h0]   * nks[g0]);
    att[ab + g0 + 1]        = a01 / (nqs[h0]   * nks[g0+1]);
    att[ab + 2048 + g0]     = a10 / (nqs[h0+1] * nks[g0]);
    att[ab + 2048 + g0 + 1] = a11 / (nqs[h0+1] * nks[g0+1]);
}

// ---------------------------------------------------------------------------
// energy_W: per (patch, row h): E[w][g] = qn(h,w) . kn(h,g)
// writes att[p][h][w][32..63]
// ---------------------------------------------------------------------------
__global__ __launch_bounds__(256) void energy_W(
    const float* __restrict__ q_t, const float* __restrict__ k_t,
    const float* __restrict__ nq, const float* __restrict__ nk,
    float* __restrict__ att)
{
    __shared__ float Qs[32][129], Ks[32][129];
    __shared__ float nqs[32], nks[32];
    const int h = blockIdx.x, p = blockIdx.y;
    const int b = p >> 4, pi = (p >> 2) & 3, pj = p & 3;
    const int gh = pi*32 + h;
    const size_t rowpos = (size_t)b*Nn + (size_t)gh*Ww + pj*32;
    const int t = threadIdx.x;
    {
        const int wl = t >> 3;
        const int c0 = (t & 7) * 16;
        const size_t base = (rowpos + wl) * CQ + c0;
        #pragma unroll
        for (int u = 0; u < 16; u += 4) {
            float4 qa = *(const float4*)&q_t[base + u];
            float4 ka = *(const float4*)&k_t[base + u];
            Qs[wl][c0+u]=qa.x; Qs[wl][c0+u+1]=qa.y; Qs[wl][c0+u+2]=qa.z; Qs[wl][c0+u+3]=qa.w;
            Ks[wl][c0+u]=ka.x; Ks[wl][c0+u+1]=ka.y; Ks[wl][c0+u+2]=ka.z; Ks[wl][c0+u+3]=ka.w;
        }
    }
    if (t < 32) { nqs[t] = nq[rowpos + t]; nks[t] = nk[rowpos + t]; }
    __syncthreads();
    const int w0 = (t & 15) * 2, g0 = (t >> 4) * 2;
    float a00=0,a01=0,a10=0,a11=0;
    #pragma unroll 4
    for (int c = 0; c < CQ; c++) {
        float q0 = Qs[w0][c], q1 = Qs[w0+1][c];
        float k0 = Ks[g0][c], k1 = Ks[g0+1][c];
        a00 = fmaf(q0,k0,a00); a01 = fmaf(q0,k1,a01);
        a10 = fmaf(q1,k0,a10); a11 = fmaf(q1,k1,a11);
    }
    const size_t ab = (((size_t)p*32 + h)*32 + w0)*64 + 32;
    att[ab + g0]          = a00 / (nqs[w0]   * nks[g0]);
    att[ab + g0 + 1]      = a01 / (nqs[w0]   * nks[g0+1]);
    att[ab + 64 + g0]     = a10 / (nqs[w0+1] * nks[g0]);
    att[ab + 64 + g0 + 1] = a11 / (nqs[w0+1] * nks[g0+1]);
}

// ---------------------------------------------------------------------------
// softmax over the 64 concatenated energies per (patch, position)
// ---------------------------------------------------------------------------
__global__ __launch_bounds__(256) void softmax64(float* __restrict__ att)
{
    const size_t idx = (size_t)blockIdx.x * 256 + threadIdx.x;  // < 65536
    float* row = att + idx * 64;
    float v[64];
    float m = -1e30f;
    #pragma unroll
    for (int i = 0; i < 64; i += 4) {
        float4 x4 = *(const float4*)&row[i];
        v[i]=x4.x; v[i+1]=x4.y; v[i+2]=x4.z; v[i+3]=x4.w;
        m = fmaxf(m, fmaxf(fmaxf(x4.x,x4.y), fmaxf(x4.z,x4.w)));
    }
    float s = 0.f;
    #pragma unroll
    for (int i = 0; i < 64; i++) { v[i] = __expf(v[i] - m); s += v[i]; }
    const float inv = 1.f / s;
    #pragma unroll
    for (int i = 0; i < 64; i += 4) {
        float4 x4 = {v[i]*inv, v[i+1]*inv, v[i+2]*inv, v[i+3]*inv};
        *(float4*)&row[i] = x4;
    }
}

// ---------------------------------------------------------------------------
// outH: per (patch, w): out[c][h] = sum_g V[g][c] * attH[h][g]  ('=' write)
// ---------------------------------------------------------------------------
__global__ __launch_bounds__(256) void cc_outH(
    const float* __restrict__ v_t, const float* __restrict__ att,
    float* __restrict__ x1)
{
    __shared__ float Vs[32][256];
    __shared__ float At[32][33];
    const int w = blockIdx.x, p = blockIdx.y;
    const int b = p >> 4, pi = (p >> 2) & 3, pj = p & 3;
    const int gw = pj*32 + w;
    const int t = threadIdx.x;
    {
        const int hh = t >> 3, g0 = (t & 7) * 4;
        const float* arow = att + (((size_t)p*32 + hh)*32 + w)*64 + g0;
        float4 a = *(const float4*)arow;
        At[g0][hh]=a.x; At[g0+1][hh]=a.y; At[g0+2][hh]=a.z; At[g0+3][hh]=a.w;
    }
    const int s  = t & 63, hg = t >> 6;
    const int cl = s * 4, h0 = hg * 8;
    for (int half = 0; half < 2; half++) {
        __syncthreads();
        {
            const int g = t >> 3, c0 = (t & 7) * 32;
            const float* src = v_t + ((size_t)b*Nn + (size_t)(pi*32 + g)*Ww + gw)*Cc + half*256 + c0;
            #pragma unroll
            for (int u = 0; u < 32; u += 4)
                *(float4*)&Vs[g][c0+u] = *(const float4*)&src[u];
        }
        __syncthreads();
        float acc[8][4];
        #pragma unroll
        for (int i = 0; i < 8; i++) { acc[i][0]=0.f; acc[i][1]=0.f; acc[i][2]=0.f; acc[i][3]=0.f; }
        #pragma unroll 4
        for (int g = 0; g < 32; g++) {
            const float4 va = *(const float4*)&Vs[g][cl];
            #pragma unroll
            for (int hh = 0; hh < 8; hh++) {
                const float a = At[g][h0+hh];
                acc[hh][0] = fmaf(va.x, a, acc[hh][0]);
                acc[hh][1] = fmaf(va.y, a, acc[hh][1]);
                acc[hh][2] = fmaf(va.z, a, acc[hh][2]);
                acc[hh][3] = fmaf(va.w, a, acc[hh][3]);
            }
        }
        #pragma unroll
        for (int hh = 0; hh < 8; hh++) {
            float4 o = {acc[hh][0], acc[hh][1], acc[hh][2], acc[hh][3]};
            *(float4*)&x1[((size_t)b*Nn + (size_t)(pi*32 + h0+hh)*Ww + gw)*Cc + half*256 + cl] = o;
        }
    }
}

// ---------------------------------------------------------------------------
// outW: per (patch, h): out[c][w] += sum_g V[g][c] * attW[w][g]  (+= write)
// ---------------------------------------------------------------------------
__global__ __launch_bounds__(256) void cc_outW(
    const float* __restrict__ v_t, const float* __restrict__ att,
    float* __restrict__ x1)
{
    __shared__ float Vs[32][256];
    __shared__ float At[32][33];
    const int h = blockIdx.x, p = blockIdx.y;
    const int b = p >> 4, pi = (p >> 2) & 3, pj = p & 3;
    const int gh = pi*32 + h;
    const size_t rowpos = (size_t)b*Nn + (size_t)gh*Ww + pj*32;
    const int t = threadIdx.x;
    {
        const int wl = t >> 3, g0 = (t & 7) * 4;
        const float* arow = att + (((size_t)p*32 + h)*32 + wl)*64 + 32 + g0;
        float4 a = *(const float4*)arow;
        At[g0][wl]=a.x; At[g0+1][wl]=a.y; At[g0+2][wl]=a.z; At[g0+3][wl]=a.w;
    }
    const int s  = t & 63, wg = t >> 6;
    const int cl = s * 4, w0 = wg * 8;
    for (int half = 0; half < 2; half++) {
        __syncthreads();
        {
            const int g = t >> 3, c0 = (t & 7) * 32;
            const float* src = v_t + (rowpos + g)*Cc + half*256 + c0;
            #pragma unroll
            for (int u = 0; u < 32; u += 4)
                *(float4*)&Vs[g][c0+u] = *(const float4*)&src[u];
        }
        __syncthreads();
        float acc[8][4];
        #pragma unroll
        for (int i = 0; i < 8; i++) { acc[i][0]=0.f; acc[i][1]=0.f; acc[i][2]=0.f; acc[i][3]=0.f; }
        #pragma unroll 4
        for (int g = 0; g < 32; g++) {
            const float4 va = *(const float4*)&Vs[g][cl];
            #pragma unroll
            for (int ww = 0; ww < 8; ww++) {
                const float a = At[g][w0+ww];
                acc[ww][0] = fmaf(va.x, a, acc[ww][0]);
                acc[ww][1] = fmaf(va.y, a, acc[ww][1]);
                acc[ww][2] = fmaf(va.z, a, acc[ww][2]);
                acc[ww][3] = fmaf(va.w, a, acc[ww][3]);
            }
        }
        #pragma unroll
        for (int ww = 0; ww < 8; ww++) {
            float* op = x1 + (rowpos + w0+ww)*Cc + half*256 + cl;
            float4 r = *(const float4*)op;
            r.x += acc[ww][0]; r.y += acc[ww][1]; r.z += acc[ww][2]; r.w += acc[ww][3];
            *(float4*)op = r;
        }
    }
}

// ---------------------------------------------------------------------------
// CAM
// ---------------------------------------------------------------------------
__global__ void zero_kernel(float* __restrict__ p, int n)
{
    const int i = blockIdx.x * 256 + threadIdx.x;
    if (i < n) p[i] = 0.f;
}

__global__ __launch_bounds__(256) void cam_normacc(
    const float* __restrict__ x1, float* __restrict__ nf2)
{
    const int b = blockIdx.x >> 6, ch = blockIdx.x & 63;
    const int t = threadIdx.x;
    const float* base = x1 + ((size_t)b*Nn + (size_t)ch*256)*Cc;
    float s0 = 0.f, s1 = 0.f;
    #pragma unroll 8
    for (int r = 0; r < 256; r++) {
        const float v0 = base[(size_t)r*Cc + t];
        const float v1 = base[(size_t)r*Cc + t + 256];
        s0 = fmaf(v0, v0, s0);
        s1 = fmaf(v1, v1, s1);
    }
    atomicAdd(&nf2[b*Cc + t],       s0);
    atomicAdd(&nf2[b*Cc + t + 256], s1);
}

// Gram partials: Gp[(kc*4+b)][i][j] = sum over n-chunk of f[i][n]*f[j][n]
__global__ __launch_bounds__(256) void cam_gram(
    const float* __restrict__ x1, float* __restrict__ Gp)
{
    __shared__ float As[16][132], Bs[16][132];
    const int t = threadIdx.x, ty = t >> 4, tx = t & 15;
    const int i0 = blockIdx.x * 128, j0 = blockIdx.y * 128;
    const int b = blockIdx.z >> 3, kc = blockIdx.z & 7;
    const float* xb = x1 + (size_t)b*Nn*Cc;
    float acc[8][8];
    #pragma unroll
    for (int i = 0; i < 8; i++)
        #pragma unroll
        for (int j = 0; j < 8; j++) acc[i][j] = 0.f;

    const int kend = kc*2048 + 2048;
    for (int k0 = kc*2048; k0 < kend; k0 += 16) {
        const int kk = t >> 4, cg = (t & 15) * 8;
        {
            const float* src = xb + (size_t)(k0+kk)*Cc + i0 + cg;
            *(float4*)&As[kk][cg]   = *(const float4*)src;
            *(float4*)&As[kk][cg+4] = *(const float4*)(src+4);
        }
        {
            const float* src = xb + (size_t)(k0+kk)*Cc + j0 + cg;
            *(float4*)&Bs[kk][cg]   = *(const float4*)src;
            *(float4*)&Bs[kk][cg+4] = *(const float4*)(src+4);
        }
        __syncthreads();
        #pragma unroll
        for (int k2 = 0; k2 < 16; k2++) {
            float4 alo = *(const float4*)&As[k2][ty*4];
            float4 ahi = *(const float4*)&As[k2][64 + ty*4];
            float4 blo = *(const float4*)&Bs[k2][tx*4];
            float4 bhi = *(const float4*)&Bs[k2][64 + tx*4];
            float av[8] = {alo.x,alo.y,alo.z,alo.w,ahi.x,ahi.y,ahi.z,ahi.w};
            float bw[8] = {blo.x,blo.y,blo.z,blo.w,bhi.x,bhi.y,bhi.z,bhi.w};
            #pragma unroll
            for (int i = 0; i < 8; i++)
                #pragma unroll
                for (int j = 0; j < 8; j++)
                    acc[i][j] = fmaf(av[i], bw[j], acc[i][j]);
        }
        __syncthreads();
    }
    float* gp = Gp + (size_t)(kc*4 + b) * 512 * 512;
    #pragma unroll
    for (int hi = 0; hi < 2; hi++)
        #pragma unroll
        for (int ii = 0; ii < 4; ii++) {
            const int row = i0 + hi*64 + ty*4 + ii;
            float* rp = gp + (size_t)row*512 + j0;
            const int ai = hi*4 + ii;
            float4 o0 = {acc[ai][0], acc[ai][1], acc[ai][2], acc[ai][3]};
            float4 o1 = {acc[ai][4], acc[ai][5], acc[ai][6], acc[ai][7]};
            *(float4*)&rp[tx*4]      = o0;
            *(float4*)&rp[64 + tx*4] = o1;
        }
}

// reduce partials, divide by norms, softmax over j -> P[b][i][j]
__global__ __launch_bounds__(256) void cam_softmax(
    const float* __restrict__ Gp, const float* __restrict__ nf2,
    float* __restrict__ P)
{
    const int b = blockIdx.x >> 9, i = blockIdx.x & 511;
    const int t = threadIdx.x;
    __shared__ float red[8];
    const size_t roff = ((size_t)b*512 + i) * 512;
    float v0 = 0.f, v1 = 0.f;
    #pragma unroll
    for (int kc = 0; kc < 8; kc++) {
        const float* gp = Gp + (size_t)(kc*4 + b)*512*512 + (size_t)i*512;
        v0 += gp[t];
        v1 += gp[t + 256];
    }
    const float nfi = sqrtf(nf2[b*512 + i]) + EPSf;
    const float nj0 = sqrtf(nf2[b*512 + t]) + EPSf;
    const float nj1 = sqrtf(nf2[b*512 + t + 256]) + EPSf;
    float e0 = v0 / (nfi*nj0), e1 = v1 / (nfi*nj1);
    float m = fmaxf(e0, e1);
    #pragma unroll
    for (int o = 32; o > 0; o >>= 1) m = fmaxf(m, __shfl_xor(m, o, 64));
    if ((t & 63) == 0) red[t >> 6] = m;
    __syncthreads();
    m = fmaxf(fmaxf(red[0], red[1]), fmaxf(red[2], red[3]));
    float p0 = __expf(e0 - m), p1 = __expf(e1 - m);
    float s = p0 + p1;
    #pragma unroll
    for (int o = 32; o > 0; o >>= 1) s += __shfl_xor(s, o, 64);
    if ((t & 63) == 0) red[4 + (t >> 6)] = s;
    __syncthreads();
    s = red[4] + red[5] + red[6] + red[7];
    const float inv = 1.f / s;
    P[roff + t]       = p0 * inv;
    P[roff + t + 256] = p1 * inv;
}

// out[b][i][n] = gamma * sum_j P[i][j]*f[j][n] + f[i][n]   (standard layout)
__global__ __launch_bounds__(256) void cam_out(
    const float* __restrict__ P, const float* __restrict__ x1,
    const float* __restrict__ gamma, float* __restrict__ out)
{
    __shared__ float As[16][132], Bs[16][132];
    __shared__ float Rs[128][34];
    const int t = threadIdx.x, ty = t >> 4, tx = t & 15;
    const int n0 = blockIdx.x * 128, i0 = blockIdx.y * 128, b = blockIdx.z;
    float acc[8][8];
    #pragma unroll
    for (int i = 0; i < 8; i++)
        #pragma unroll
        for (int j = 0; j < 8; j++) acc[i][j] = 0.f;

    for (int k0 = 0; k0 < 512; k0 += 16) {
        {
            // As[kk][i] = P[(b,i0+i)][k0+kk]
            const int r = t >> 1, kk0 = (t & 1) * 8;
            const float* src = P + ((size_t)b*512 + i0 + r)*512 + k0 + kk0;
            float4 v0 = *(const float4*)src;
            float4 v1 = *(const float4*)(src + 4);
            As[kk0+0][r]=v0.x; As[kk0+1][r]=v0.y; As[kk0+2][r]=v0.z; As[kk0+3][r]=v0.w;
            As[kk0+4][r]=v1.x; As[kk0+5][r]=v1.y; As[kk0+6][r]=v1.z; As[kk0+7][r]=v1.w;
        }
        {
            // Bs[kk][n] = f[k0+kk][n0+n] = x1[(b,n0+n)][k0+kk]
            const int cn = t >> 1, kk0 = (t & 1) * 8;
            const float* src = x1 + ((size_t)b*Nn + n0 + cn)*Cc + k0 + kk0;
            float4 v0 = *(const float4*)src;
            float4 v1 = *(const float4*)(src + 4);
            Bs[kk0+0][cn]=v0.x; Bs[kk0+1][cn]=v0.y; Bs[kk0+2][cn]=v0.z; Bs[kk0+3][cn]=v0.w;
            Bs[kk0+4][cn]=v1.x; Bs[kk0+5][cn]=v1.y; Bs[kk0+6][cn]=v1.z; Bs[kk0+7][cn]=v1.w;
        }
        __syncthreads();
        #pragma unroll
        for (int k2 = 0; k2 < 16; k2++) {
            float4 alo = *(const float4*)&As[k2][ty*4];
            float4 ahi = *(const float4*)&As[k2][64 + ty*4];
            float4 blo = *(const float4*)&Bs[k2][tx*4];
            float4 bhi = *(const float4*)&Bs[k2][64 + tx*4];
            float av[8] = {alo.x,alo.y,alo.z,alo.w,ahi.x,ahi.y,ahi.z,ahi.w};
            float bw[8] = {blo.x,blo.y,blo.z,blo.w,bhi.x,bhi.y,bhi.z,bhi.w};
            #pragma unroll
            for (int i = 0; i < 8; i++)
                #pragma unroll
                for (int j = 0; j < 8; j++)
                    acc[i][j] = fmaf(av[i], bw[j], acc[i][j]);
        }
        __syncthreads();
    }

    const float gm = gamma[0];
    for (int ic = 0; ic < 4; ic++) {
        {
            // stage residual chunk: Rs[n_local][i_local32] = f[i0+ic*32+il][n0+n]
            const int r = t >> 1, c0v = (t & 1) * 16;
            const float* src = x1 + ((size_t)b*Nn + n0 + r)*Cc + i0 + ic*32 + c0v;
            float4 v0 = *(const float4*)src;
            float4 v1 = *(const float4*)(src + 4);
            float4 v2 = *(const float4*)(src + 8);
            float4 v3 = *(const float4*)(src + 12);
            Rs[r][c0v+ 0]=v0.x; Rs[r][c0v+ 1]=v0.y; Rs[r][c0v+ 2]=v0.z; Rs[r][c0v+ 3]=v0.w;
            Rs[r][c0v+ 4]=v1.x; Rs[r][c0v+ 5]=v1.y; Rs[r][c0v+ 6]=v1.z; Rs[r][c0v+ 7]=v1.w;
            Rs[r][c0v+ 8]=v2.x; Rs[r][c0v+ 9]=v2.y; Rs[r][c0v+10]=v2.z; Rs[r][c0v+11]=v2.w;
            Rs[r][c0v+12]=v3.x; Rs[r][c0v+13]=v3.y; Rs[r][c0v+14]=v3.z; Rs[r][c0v+15]=v3.w;
        }
        __syncthreads();
        const int half = ic >> 1, icl = ic & 1;
        if ((ty >> 3) == icl) {
            #pragma unroll
            for (int ii = 0; ii < 4; ii++) {
                const int rl  = 4*(ty & 7) + ii;
                const int row = half*64 + icl*32 + rl;
                const int ai  = half*4 + ii;
                #pragma unroll
                for (int jh = 0; jh < 2; jh++) {
                    const int cb = jh*64 + tx*4;
                    float4 o;
                    o.x = fmaf(gm, acc[ai][jh*4+0], Rs[cb+0][rl]);
                    o.y = fmaf(gm, acc[ai][jh*4+1], Rs[cb+1][rl]);
                    o.z = fmaf(gm, acc[ai][jh*4+2], Rs[cb+2][rl]);
                    o.w = fmaf(gm, acc[ai][jh*4+3], Rs[cb+3][rl]);
                    *(float4*)&out[((size_t)b*512 + i0 + row)*Nn + n0 + cb] = o;
                }
            }
        }
        __syncthreads();
    }
}

// ---------------------------------------------------------------------------
extern "C" void kernel_launch(void* const* d_in, const int* in_sizes, int n_in,
                              void* d_out, int out_size, void* d_ws, size_t ws_size,
                              hipStream_t stream)
{
    (void)in_sizes; (void)n_in; (void)out_size; (void)ws_size;
    const float* x    = (const float*)d_in[0];
    const float* wqp  = (const float*)d_in[1];
    const float* bqp  = (const float*)d_in[2];
    const float* wkp  = (const float*)d_in[3];
    const float* bkp  = (const float*)d_in[4];
    const float* wvp  = (const float*)d_in[5];
    const float* bvp  = (const float*)d_in[6];
    const float* gmp  = (const float*)d_in[7];
    float* out = (float*)d_out;

    float* ws  = (float*)d_ws;
    float* q_t = ws;                                  //  8,388,608 floats
    float* k_t = q_t + (size_t)Bn*Nn*CQ;              //  8,388,608
    float* v_t = k_t + (size_t)Bn*Nn*CQ;              // 33,554,432
    float* x1  = v_t + (size_t)Bn*Nn*Cc;              // 33,554,432
    float* att = x1  + (size_t)Bn*Nn*Cc;              //  4,194,304
    float* nq  = att + (size_t)NPATCH*1024*64;        //     65,536
    float* nk  = nq  + (size_t)Bn*Nn;                 //     65,536
    // CAM scratch aliases the q_t/k_t region (free after iteration 2 energies)
    float* nf2 = q_t;                                 //      2,048
    float* Gp  = q_t + 4096;                          //  8,388,608
    float* P   = Gp + (size_t)8*4*512*512;            //  1,048,576

    for (int it = 0; it < 2; it++) {
        if (it == 0)
            qkv_gemm<false><<<dim3(128,6,4), 256, 0, stream>>>(x,  wqp,bqp,wkp,bkp,wvp,bvp, q_t,k_t,v_t);
        else
            qkv_gemm<true ><<<dim3(128,6,4), 256, 0, stream>>>(x1, wqp,bqp,wkp,bkp,wvp,bvp, q_t,k_t,v_t);
        qk_norms <<<dim3(256),   256, 0, stream>>>(q_t, k_t, nq, nk);
        energy_H <<<dim3(32,64), 256, 0, stream>>>(q_t, k_t, nq, nk, att);
        energy_W <<<dim3(32,64), 256, 0, stream>>>(q_t, k_t, nq, nk, att);
        softmax64<<<dim3(256),   256, 0, stream>>>(att);
        cc_outH  <<<dim3(32,64), 256, 0, stream>>>(v_t, att, x1);
        cc_outW  <<<dim3(32,64), 256, 0, stream>>>(v_t, att, x1);
    }
    zero_kernel <<<dim3(8),        256, 0, stream>>>(nf2, 2048);
    cam_normacc <<<dim3(256),      256, 0, stream>>>(x1, nf2);
    cam_gram    <<<dim3(4,4,32),   256, 0, stream>>>(x1, Gp);
    cam_softmax <<<dim3(2048),     256, 0, stream>>>(Gp, nf2, P);
    cam_out     <<<dim3(128,4,4),  256, 0, stream>>>(P, x1, gmp, out);
}

// Round 6
// 1467.680 us; speedup vs baseline: 1.7023x; 1.7023x over previous
//
#include <hip/hip_runtime.h>
#include <math.h>

// Problem constants (shapes fixed by reference setup_inputs)
constexpr int Bn = 4;
constexpr int Cc = 512;
constexpr int CQ = 128;
constexpr int Hh = 128, Ww = 128;
constexpr int Nn = Hh * Ww;        // 16384
constexpr int NPATCH = 64;         // B * 4 * 4
constexpr float EPSf = 1e-10f;

typedef unsigned int u32;
typedef unsigned short u16;
typedef __attribute__((ext_vector_type(8))) short bf16x8;
typedef __attribute__((ext_vector_type(4))) float f32x4;

__device__ inline u16 f2bf(float f) {
    u32 u = __float_as_uint(f);
    u32 r = u + 0x7fffu + ((u >> 16) & 1u);
    return (u16)(r >> 16);
}
__device__ inline float bf2f(u16 h) { return __uint_as_float((u32)h << 16); }

#define GLOAD16(g, l) __builtin_amdgcn_global_load_lds( \
    (const __attribute__((address_space(1))) u32*)(g), \
    (__attribute__((address_space(3))) u32*)(l), 16, 0, 0)

// ===========================================================================
// Converters: fp32 -> split bf16 (hi + lo), various layouts
// ===========================================================================

// weights: wq[128][512], wk[128][512], wv[512][512] -> wh/wl [768][512], bcat[768]
__global__ __launch_bounds__(256) void conv_w(
    const float* __restrict__ wq, const float* __restrict__ bq,
    const float* __restrict__ wk, const float* __restrict__ bk,
    const float* __restrict__ wv, const float* __restrict__ bv,
    u16* __restrict__ wh, u16* __restrict__ wl, float* __restrict__ bcat)
{
    const int oc = blockIdx.x;  // 0..767
    const float* src; float bias;
    if (oc < 128)      { src = wq + (size_t)oc * 512;        bias = bq[oc]; }
    else if (oc < 256) { src = wk + (size_t)(oc-128) * 512;  bias = bk[oc-128]; }
    else               { src = wv + (size_t)(oc-256) * 512;  bias = bv[oc-256]; }
    for (int c = threadIdx.x; c < 512; c += 256) {
        float v = src[c];
        u16 h = f2bf(v);
        wh[(size_t)oc*512 + c] = h;
        wl[(size_t)oc*512 + c] = f2bf(v - bf2f(h));
    }
    if (threadIdx.x == 0) bcat[oc] = bias;
}

// x [b][C][N] fp32 -> xh/xl channel-last [(b,n)][C] bf16 (transpose-convert)
__global__ __launch_bounds__(256) void conv_x_t(
    const float* __restrict__ x, u16* __restrict__ xh, u16* __restrict__ xl)
{
    __shared__ float T[64][65];
    const int n0 = blockIdx.x * 64, c0 = blockIdx.y * 64, b = blockIdx.z;
    const int t = threadIdx.x;
    {
        const int cc = t >> 2, nn = (t & 3) * 16;
        const float* s = x + ((size_t)b*Cc + c0 + cc)*Nn + n0 + nn;
        #pragma unroll
        for (int u = 0; u < 16; u += 4) {
            float4 v = *(const float4*)(s + u);
            T[cc][nn+u]=v.x; T[cc][nn+u+1]=v.y; T[cc][nn+u+2]=v.z; T[cc][nn+u+3]=v.w;
        }
    }
    __syncthreads();
    {
        const int nn = t >> 2, cc0 = (t & 3) * 16;
        u16 hs[16] __attribute__((aligned(16)));
        u16 ls[16] __attribute__((aligned(16)));
        #pragma unroll
        for (int e = 0; e < 16; e++) {
            float v = T[cc0+e][nn];
            u16 h = f2bf(v);
            hs[e] = h; ls[e] = f2bf(v - bf2f(h));
        }
        const size_t o = ((size_t)b*Nn + n0 + nn)*Cc + c0 + cc0;
        *(uint4*)&xh[o]   = *(const uint4*)&hs[0];
        *(uint4*)&xh[o+8] = *(const uint4*)&hs[8];
        *(uint4*)&xl[o]   = *(const uint4*)&ls[0];
        *(uint4*)&xl[o+8] = *(const uint4*)&ls[8];
    }
}

// flat channel-last fp32 -> hi/lo bf16 (no transpose)
__global__ __launch_bounds__(256) void conv_cl(
    const float* __restrict__ s, u16* __restrict__ h, u16* __restrict__ l, long n)
{
    const long i = (((long)blockIdx.x << 8) + threadIdx.x) << 3;
    if (i >= n) return;
    float4 a = *(const float4*)(s + i), b4 = *(const float4*)(s + i + 4);
    float v[8] = {a.x,a.y,a.z,a.w,b4.x,b4.y,b4.z,b4.w};
    u16 hs[8] __attribute__((aligned(16)));
    u16 ls[8] __attribute__((aligned(16)));
    #pragma unroll
    for (int e = 0; e < 8; e++) {
        u16 hh = f2bf(v[e]);
        hs[e] = hh; ls[e] = f2bf(v[e] - bf2f(hh));
    }
    *(uint4*)&h[i] = *(const uint4*)hs;
    *(uint4*)&l[i] = *(const uint4*)ls;
}

// x1 channel-last [(b,n)][C] fp32 -> fTh/fTl [b][C][N] bf16 (transpose-convert)
__global__ __launch_bounds__(256) void conv_t_cl(
    const float* __restrict__ x1, u16* __restrict__ th, u16* __restrict__ tl)
{
    __shared__ float T[64][65];
    const int n0 = blockIdx.x * 64, c0 = blockIdx.y * 64, b = blockIdx.z;
    const int t = threadIdx.x;
    {
        const int nn = t >> 2, cc0 = (t & 3) * 16;
        const float* s = x1 + ((size_t)b*Nn + n0 + nn)*Cc + c0 + cc0;
        #pragma unroll
        for (int u = 0; u < 16; u += 4) {
            float4 v = *(const float4*)(s + u);
            T[nn][cc0+u]=v.x; T[nn][cc0+u+1]=v.y; T[nn][cc0+u+2]=v.z; T[nn][cc0+u+3]=v.w;
        }
    }
    __syncthreads();
    {
        const int cc = t >> 2, nn0 = (t & 3) * 16;
        u16 hs[16] __attribute__((aligned(16)));
        u16 ls[16] __attribute__((aligned(16)));
        #pragma unroll
        for (int e = 0; e < 16; e++) {
            float v = T[nn0+e][cc];
            u16 h = f2bf(v);
            hs[e] = h; ls[e] = f2bf(v - bf2f(h));
        }
        const size_t o = ((size_t)b*Cc + c0 + cc)*Nn + n0 + nn0;
        *(uint4*)&th[o]   = *(const uint4*)&hs[0];
        *(uint4*)&th[o+8] = *(const uint4*)&hs[8];
        *(uint4*)&tl[o]   = *(const uint4*)&ls[0];
        *(uint4*)&tl[o+8] = *(const uint4*)&ls[8];
    }
}

// ===========================================================================
// Split-bf16 MFMA GEMM kernels. Common structure:
//  - 128x128 tile, BK=32, 4 waves, each wave 64x64 (4x4 frags of 16x16x32)
//  - LDS rows: 128 bytes = [hi 64B | lo 64B], XOR-swizzle byte^=((row&7)<<4)
//  - staging: global_load_lds w16, pre-swizzled per-lane global source
//  - 3 MFMA per fragment pair: Ah*Bh + Ah*Bl + Al*Bh (fp32 accum)
// ===========================================================================

// Fused QKV: A = x channel-last hi/lo [(b,n)][512]; B = W [768][512] hi/lo.
__global__ __launch_bounds__(256) void qkv_mfma(
    const u16* __restrict__ xh, const u16* __restrict__ xl,
    const u16* __restrict__ wh, const u16* __restrict__ wl,
    const float* __restrict__ bcat,
    float* __restrict__ q_t, float* __restrict__ k_t, float* __restrict__ v_t)
{
    __shared__ char Ash[16384];
    __shared__ char Bsh[16384];
    const int t = threadIdx.x, lane = t & 63, wid = t >> 6;
    const int n0 = blockIdx.x * 128, oc0 = blockIdx.y * 128, b = blockIdx.z;
    const size_t bN = (size_t)b * Nn;

    float* outp; int ocb, OC;
    if (oc0 == 0)        { outp = q_t; ocb = 0;         OC = CQ; }
    else if (oc0 == 128) { outp = k_t; ocb = 0;         OC = CQ; }
    else                 { outp = v_t; ocb = oc0 - 256; OC = Cc; }

    // staging sources (pre-swizzled): physical byte p -> logical chunk ^ (row&7)
    const u16* sA[4]; const u16* sB[4];
    #pragma unroll
    for (int q = 0; q < 4; q++) {
        const int p = ((wid*4 + q) << 10) + lane*16;
        const int row = p >> 7;
        const int lchunk = ((p >> 4) & 7) ^ (row & 7);
        const int ko = (lchunk & 3) * 8;
        sA[q] = ((lchunk < 4) ? xh : xl) + (bN + n0 + row)*(size_t)Cc + ko;
        sB[q] = ((lchunk < 4) ? wh : wl) + (size_t)(oc0 + row)*Cc + ko;
    }

    // fragment LDS byte offsets (k-independent)
    const int wr = wid >> 1, wc = wid & 1;
    int aoff[4], boff[4];
    #pragma unroll
    for (int m = 0; m < 4; m++) {
        const int ra = (wr << 6) + (m << 4) + (lane & 15);
        aoff[m] = (ra << 7) + ((((lane >> 4) << 4)) ^ ((ra & 7) << 4));
        const int rb = (wc << 6) + (m << 4) + (lane & 15);
        boff[m] = (rb << 7) + ((((lane >> 4) << 4)) ^ ((rb & 7) << 4));
    }

    f32x4 acc[4][4];
    #pragma unroll
    for (int m = 0; m < 4; m++)
        #pragma unroll
        for (int n = 0; n < 4; n++) acc[m][n] = (f32x4){0.f, 0.f, 0.f, 0.f};

    for (int ks = 0; ks < 16; ks++) {
        if (ks) __syncthreads();
        #pragma unroll
        for (int q = 0; q < 4; q++) {
            GLOAD16(sA[q], Ash + ((wid*4 + q) << 10));
            GLOAD16(sB[q], Bsh + ((wid*4 + q) << 10));
            sA[q] += 32; sB[q] += 32;
        }
        __syncthreads();
        bf16x8 ah[4], al[4], bh[4], bl[4];
        #pragma unroll
        for (int m = 0; m < 4; m++) {
            ah[m] = *(const bf16x8*)(Ash + aoff[m]);
            al[m] = *(const bf16x8*)(Ash + (aoff[m] ^ 64));
            bh[m] = *(const bf16x8*)(Bsh + boff[m]);
            bl[m] = *(const bf16x8*)(Bsh + (boff[m] ^ 64));
        }
        #pragma unroll
        for (int m = 0; m < 4; m++)
            #pragma unroll
            for (int n = 0; n < 4; n++) {
                acc[m][n] = __builtin_amdgcn_mfma_f32_16x16x32_bf16(ah[m], bh[n], acc[m][n], 0, 0, 0);
                acc[m][n] = __builtin_amdgcn_mfma_f32_16x16x32_bf16(ah[m], bl[n], acc[m][n], 0, 0, 0);
                acc[m][n] = __builtin_amdgcn_mfma_f32_16x16x32_bf16(al[m], bh[n], acc[m][n], 0, 0, 0);
            }
    }

    // D layout: col = lane&15, row = (lane>>4)*4 + r
    const int col = lane & 15, rq = lane >> 4;
    #pragma unroll
    for (int n = 0; n < 4; n++) {
        const int oc = (wc << 6) + (n << 4) + col;
        const float bias = bcat[oc0 + oc];
        #pragma unroll
        for (int m = 0; m < 4; m++) {
            #pragma unroll
            for (int r = 0; r < 4; r++) {
                const int nrow = n0 + (wr << 6) + (m << 4) + (rq << 2) + r;
                outp[(bN + nrow)*OC + ocb + oc] = acc[m][n][r] + bias;
            }
        }
    }
}

// CAM Gram partials: A = B = fT [b][512][16384] hi/lo; split-K over 8 chunks.
__global__ __launch_bounds__(256) void gram_mfma(
    const u16* __restrict__ fTh, const u16* __restrict__ fTl,
    float* __restrict__ Gp)
{
    __shared__ char Ash[16384];
    __shared__ char Bsh[16384];
    const int t = threadIdx.x, lane = t & 63, wid = t >> 6;
    const int i0 = blockIdx.x * 128, j0 = blockIdx.y * 128;
    const int b = blockIdx.z >> 3, kc = blockIdx.z & 7;
    const size_t cb = (size_t)b * 512 * Nn;

    const u16* sA[4]; const u16* sB[4];
    #pragma unroll
    for (int q = 0; q < 4; q++) {
        const int p = ((wid*4 + q) << 10) + lane*16;
        const int row = p >> 7;
        const int lchunk = ((p >> 4) & 7) ^ (row & 7);
        const int ko = (lchunk & 3) * 8;
        const u16* s = (lchunk < 4) ? fTh : fTl;
        sA[q] = s + cb + (size_t)(i0 + row)*Nn + kc*2048 + ko;
        sB[q] = s + cb + (size_t)(j0 + row)*Nn + kc*2048 + ko;
    }

    const int wr = wid >> 1, wc = wid & 1;
    int aoff[4], boff[4];
    #pragma unroll
    for (int m = 0; m < 4; m++) {
        const int ra = (wr << 6) + (m << 4) + (lane & 15);
        aoff[m] = (ra << 7) + ((((lane >> 4) << 4)) ^ ((ra & 7) << 4));
        const int rb = (wc << 6) + (m << 4) + (lane & 15);
        boff[m] = (rb << 7) + ((((lane >> 4) << 4)) ^ ((rb & 7) << 4));
    }

    f32x4 acc[4][4];
    #pragma unroll
    for (int m = 0; m < 4; m++)
        #pragma unroll
        for (int n = 0; n < 4; n++) acc[m][n] = (f32x4){0.f, 0.f, 0.f, 0.f};

    for (int ks = 0; ks < 64; ks++) {
        if (ks) __syncthreads();
        #pragma unroll
        for (int q = 0; q < 4; q++) {
            GLOAD16(sA[q], Ash + ((wid*4 + q) << 10));
            GLOAD16(sB[q], Bsh + ((wid*4 + q) << 10));
            sA[q] += 32; sB[q] += 32;
        }
        __syncthreads();
        bf16x8 ah[4], al[4], bh[4], bl[4];
        #pragma unroll
        for (int m = 0; m < 4; m++) {
            ah[m] = *(const bf16x8*)(Ash + aoff[m]);
            al[m] = *(const bf16x8*)(Ash + (aoff[m] ^ 64));
            bh[m] = *(const bf16x8*)(Bsh + boff[m]);
            bl[m] = *(const bf16x8*)(Bsh + (boff[m] ^ 64));
        }
        #pragma unroll
        for (int m = 0; m < 4; m++)
            #pragma unroll
            for (int n = 0; n < 4; n++) {
                acc[m][n] = __builtin_amdgcn_mfma_f32_16x16x32_bf16(ah[m], bh[n], acc[m][n], 0, 0, 0);
                acc[m][n] = __builtin_amdgcn_mfma_f32_16x16x32_bf16(ah[m], bl[n], acc[m][n], 0, 0, 0);
                acc[m][n] = __builtin_amdgcn_mfma_f32_16x16x32_bf16(al[m], bh[n], acc[m][n], 0, 0, 0);
            }
    }

    float* gp = Gp + (size_t)(kc*4 + b) * 512 * 512;
    const int col = lane & 15, rq = lane >> 4;
    #pragma unroll
    for (int m = 0; m < 4; m++)
        #pragma unroll
        for (int r = 0; r < 4; r++) {
            const int ri = i0 + (wr << 6) + (m << 4) + (rq << 2) + r;
            #pragma unroll
            for (int n = 0; n < 4; n++)
                gp[(size_t)ri*512 + j0 + (wc << 6) + (n << 4) + col] = acc[m][n][r];
        }
}

// CAM out: A = P [b][512][512] hi/lo; B = x1 channel-last hi/lo;
// residual from fT hi+lo; out[b][i][n] = gamma*sum + residual.
__global__ __launch_bounds__(256) void camout_mfma(
    const u16* __restrict__ Ph, const u16* __restrict__ Pl,
    const u16* __restrict__ x1h, const u16* __restrict__ x1l,
    const u16* __restrict__ fTh, const u16* __restrict__ fTl,
    const float* __restrict__ gamma, float* __restrict__ out)
{
    __shared__ char Ash[16384];
    __shared__ char Bsh[16384];
    const int t = threadIdx.x, lane = t & 63, wid = t >> 6;
    const int n0 = blockIdx.x * 128, i0 = blockIdx.y * 128, b = blockIdx.z;
    const size_t bN = (size_t)b * Nn;

    const u16* sA[4]; const u16* sB[4];
    #pragma unroll
    for (int q = 0; q < 4; q++) {
        const int p = ((wid*4 + q) << 10) + lane*16;
        const int row = p >> 7;
        const int lchunk = ((p >> 4) & 7) ^ (row & 7);
        const int ko = (lchunk & 3) * 8;
        sA[q] = ((lchunk < 4) ? Ph : Pl) + ((size_t)b*512 + i0 + row)*512 + ko;
        sB[q] = ((lchunk < 4) ? x1h : x1l) + (bN + n0 + row)*(size_t)Cc + ko;
    }

    const int wr = wid >> 1, wc = wid & 1;
    int aoff[4], boff[4];
    #pragma unroll
    for (int m = 0; m < 4; m++) {
        const int ra = (wr << 6) + (m << 4) + (lane & 15);
        aoff[m] = (ra << 7) + ((((lane >> 4) << 4)) ^ ((ra & 7) << 4));
        const int rb = (wc << 6) + (m << 4) + (lane & 15);
        boff[m] = (rb << 7) + ((((lane >> 4) << 4)) ^ ((rb & 7) << 4));
    }

    f32x4 acc[4][4];
    #pragma unroll
    for (int m = 0; m < 4; m++)
        #pragma unroll
        for (int n = 0; n < 4; n++) acc[m][n] = (f32x4){0.f, 0.f, 0.f, 0.f};

    for (int ks = 0; ks < 16; ks++) {
        if (ks) __syncthreads();
        #pragma unroll
        for (int q = 0; q < 4; q++) {
            GLOAD16(sA[q], Ash + ((wid*4 + q) << 10));
            GLOAD16(sB[q], Bsh + ((wid*4 + q) << 10));
            sA[q] += 32; sB[q] += 32;
        }
        __syncthreads();
        bf16x8 ah[4], al[4], bh[4], bl[4];
        #pragma unroll
        for (int m = 0; m < 4; m++) {
            ah[m] = *(const bf16x8*)(Ash + aoff[m]);
            al[m] = *(const bf16x8*)(Ash + (aoff[m] ^ 64));
            bh[m] = *(const bf16x8*)(Bsh + boff[m]);
            bl[m] = *(const bf16x8*)(Bsh + (boff[m] ^ 64));
        }
        #pragma unroll
        for (int m = 0; m < 4; m++)
            #pragma unroll
            for (int n = 0; n < 4; n++) {
                acc[m][n] = __builtin_amdgcn_mfma_f32_16x16x32_bf16(ah[m], bh[n], acc[m][n], 0, 0, 0);
                acc[m][n] = __builtin_amdgcn_mfma_f32_16x16x32_bf16(ah[m], bl[n], acc[m][n], 0, 0, 0);
                acc[m][n] = __builtin_amdgcn_mfma_f32_16x16x32_bf16(al[m], bh[n], acc[m][n], 0, 0, 0);
            }
    }

    const float gm = gamma[0];
    const int col = lane & 15, rq = lane >> 4;
    #pragma unroll
    for (int m = 0; m < 4; m++)
        #pragma unroll
        for (int r = 0; r < 4; r++) {
            const int i = i0 + (wr << 6) + (m << 4) + (rq << 2) + r;
            const size_t rb = ((size_t)b*512 + i)*Nn;
            #pragma unroll
            for (int n = 0; n < 4; n++) {
                const int nn = n0 + (wc << 6) + (n << 4) + col;
                const float res = bf2f(fTh[rb + nn]) + bf2f(fTl[rb + nn]);
                out[rb + nn] = fmaf(gm, acc[m][n][r], res);
            }
        }
}

// ===========================================================================
// Unchanged fp32 kernels (norms, energies, softmax, CC apply, CAM softmax)
// ===========================================================================
__global__ __launch_bounds__(256) void qk_norms(
    const float* __restrict__ q_t, const float* __restrict__ k_t,
    float* __restrict__ nq, float* __restrict__ nk)
{
    const int pos = blockIdx.x * 256 + threadIdx.x;
    const float* qp = q_t + (size_t)pos * CQ;
    const float* kp = k_t + (size_t)pos * CQ;
    float sq = 0.f, sk = 0.f;
    #pragma unroll
    for (int c = 0; c < CQ; c += 4) {
        float4 a = *(const float4*)&qp[c];
        float4 bb = *(const float4*)&kp[c];
        sq += a.x*a.x + a.y*a.y + a.z*a.z + a.w*a.w;
        sk += bb.x*bb.x + bb.y*bb.y + bb.z*bb.z + bb.w*bb.w;
    }
    nq[pos] = sqrtf(sq) + EPSf;
    nk[pos] = sqrtf(sk) + EPSf;
}

__global__ __launch_bounds__(256) void energy_H(
    const float* __restrict__ q_t, const float* __restrict__ k_t,
    const float* __restrict__ nq, const float* __restrict__ nk,
    float* __restrict__ att)
{
    __shared__ float Qs[32][129], Ks[32][129];
    __shared__ float nqs[32], nks[32];
    const int w = blockIdx.x, p = blockIdx.y;
    const int b = p >> 4, pi = (p >> 2) & 3, pj = p & 3;
    const int gw = pj*32 + w;
    const int t = threadIdx.x;
    {
        const int h  = t >> 3;
        const int c0 = (t & 7) * 16;
        const size_t base = ((size_t)b*Nn + (size_t)(pi*32 + h)*Ww + gw) * CQ + c0;
        #pragma unroll
        for (int u = 0; u < 16; u += 4) {
            float4 qa = *(const float4*)&q_t[base + u];
            float4 ka = *(const float4*)&k_t[base + u];
            Qs[h][c0+u]=qa.x; Qs[h][c0+u+1]=qa.y; Qs[h][c0+u+2]=qa.z; Qs[h][c0+u+3]=qa.w;
            Ks[h][c0+u]=ka.x; Ks[h][c0+u+1]=ka.y; Ks[h][c0+u+2]=ka.z; Ks[h][c0+u+3]=ka.w;
        }
    }
    if (t < 32) {
        const size_t pp = (size_t)b*Nn + (size_t)(pi*32 + t)*Ww + gw;
        nqs[t] = nq[pp]; nks[t] = nk[pp];
    }
    __syncthreads();
    const int h0 = (t & 15) * 2, g0 = (t >> 4) * 2;
    float a00=0,a01=0,a10=0,a11=0;
    #pragma unroll 4
    for (int c = 0; c < CQ; c++) {
        float q0 = Qs[h0][c], q1 = Qs[h0+1][c];
        float k0 = Ks[g0][c], k1 = Ks[g0+1][c];
        a00 = fmaf(q0,k0,a00); a01 = fmaf(q0,k1,a01);
        a10 = fmaf(q1,k0,a10); a11 = fmaf(q1,k1,a11);
    }
    const size_t ab = (((size_t)p*32 + h0)*32 + w)*64;
    att[ab + g0]            = a00 / (nqs[h0]   * nks[g0]);
    att[ab + g0 + 1]        = a01 / (nqs[h0]   * nks[g0+1]);
    att[ab + 2048 + g0]     = a10 / (nqs[h0+1] * nks[g0]);
    att[ab + 2048 + g0 + 1] = a11 / (nqs[h0+1] * nks[g0+1]);
}

__global__ __launch_bounds__(256) void energy_W(
    const float* __restrict__ q_t, const float* __restrict__ k_t,
    const float* __restrict__ nq, const float* __restrict__ nk,
    float* __restrict__ att)
{
    __shared__ float Qs[32][129], Ks[32][129];
    __shared__ float nqs[32], nks[32];
    const int h = blockIdx.x, p = blockIdx.y;
    const int b = p >> 4, pi = (p >> 2) & 3, pj = p & 3;
    const int gh = pi*32 + h;
    const size_t rowpos = (size_t)b*Nn + (size_t)gh*Ww + pj*32;
    const int t = threadIdx.x;
    {
        const int wl = t >> 3;
        const int c0 = (t & 7) * 16;
        const size_t base = (rowpos + wl) * CQ + c0;
        #pragma unroll
        for (int u = 0; u < 16; u += 4) {
            float4 qa = *(const float4*)&q_t[base + u];
            float4 ka = *(const float4*)&k_t[base + u];
            Qs[wl][c0+u]=qa.x; Qs[wl][c0+u+1]=qa.y; Qs[wl][c0+u+2]=qa.z; Qs[wl][c0+u+3]=qa.w;
            Ks[wl][c0+u]=ka.x; Ks[wl][c0+u+1]=ka.y; Ks[wl][c0+u+2]=ka.z; Ks[wl][c0+u+3]=ka.w;
        }
    }
    if (t < 32) { nqs[t] = nq[rowpos + t]; nks[t] = nk[rowpos + t]; }
    __syncthreads();
    const int w0 = (t & 15) * 2, g0 = (t >> 4) * 2;
    float a00=0,a01=0,a10=0,a11=0;
    #pragma unroll 4
    for (int c = 0; c < CQ; c++) {
        float q0 = Qs[w0][c], q1 = Qs[w0+1][c];
        float k0 = Ks[g0][c], k1 = Ks[g0+1][c];
        a00 = fmaf(q0,k0,a00); a01 = fmaf(q0,k1,a01);
        a10 = fmaf(q1,k0,a10); a11 = fmaf(q1,k1,a11);
    }
    const size_t ab = (((size_t)p*32 + h)*32 + w0)*64 + 32;
    att[ab + g0]          = a00 / (nqs[w0]   * nks[g0]);
    att[ab + g0 + 1]      = a01 / (nqs[w0]   * nks[g0+1]);
    att[ab + 64 + g0]     = a10 / (nqs[w0+1] * nks[g0]);
    att[ab + 64 + g0 + 1] = a11 / (nqs[w0+1] * nks[g0+1]);
}

__global__ __launch_bounds__(256) void softmax64(float* __restrict__ att)
{
    const size_t idx = (size_t)blockIdx.x * 256 + threadIdx.x;
    float* row = att + idx * 64;
    float v[64];
    float m = -1e30f;
    #pragma unroll
    for (int i = 0; i < 64; i += 4) {
        float4 x4 = *(const float4*)&row[i];
        v[i]=x4.x; v[i+1]=x4.y; v[i+2]=x4.z; v[i+3]=x4.w;
        m = fmaxf(m, fmaxf(fmaxf(x4.x,x4.y), fmaxf(x4.z,x4.w)));
    }
    float s = 0.f;
    #pragma unroll
    for (int i = 0; i < 64; i++) { v[i] = __expf(v[i] - m); s += v[i]; }
    const float inv = 1.f / s;
    #pragma unroll
    for (int i = 0; i < 64; i += 4) {
        float4 x4 = {v[i]*inv, v[i+1]*inv, v[i+2]*inv, v[i+3]*inv};
        *(float4*)&row[i] = x4;
    }
}

__global__ __launch_bounds__(256) void cc_outH(
    const float* __restrict__ v_t, const float* __restrict__ att,
    float* __restrict__ x1)
{
    __shared__ float Vs[32][256];
    __shared__ float At[32][33];
    const int w = blockIdx.x, p = blockIdx.y;
    const int b = p >> 4, pi = (p >> 2) & 3, pj = p & 3;
    const int gw = pj*32 + w;
    const int t = threadIdx.x;
    {
        const int hh = t >> 3, g0 = (t & 7) * 4;
        const float* arow = att + (((size_t)p*32 + hh)*32 + w)*64 + g0;
        float4 a = *(const float4*)arow;
        At[g0][hh]=a.x; At[g0+1][hh]=a.y; At[g0+2][hh]=a.z; At[g0+3][hh]=a.w;
    }
    const int s  = t & 63, hg = t >> 6;
    const int cl = s * 4, h0 = hg * 8;
    for (int half = 0; half < 2; half++) {
        __syncthreads();
        {
            const int g = t >> 3, c0 = (t & 7) * 32;
            const float* src = v_t + ((size_t)b*Nn + (size_t)(pi*32 + g)*Ww + gw)*Cc + half*256 + c0;
            #pragma unroll
            for (int u = 0; u < 32; u += 4)
                *(float4*)&Vs[g][c0+u] = *(const float4*)&src[u];
        }
        __syncthreads();
        float acc[8][4];
        #pragma unroll
        for (int i = 0; i < 8; i++) { acc[i][0]=0.f; acc[i][1]=0.f; acc[i][2]=0.f; acc[i][3]=0.f; }
        #pragma unroll 4
        for (int g = 0; g < 32; g++) {
            const float4 va = *(const float4*)&Vs[g][cl];
            #pragma unroll
            for (int hh = 0; hh < 8; hh++) {
                const float a = At[g][h0+hh];
                acc[hh][0] = fmaf(va.x, a, acc[hh][0]);
                acc[hh][1] = fmaf(va.y, a, acc[hh][1]);
                acc[hh][2] = fmaf(va.z, a, acc[hh][2]);
                acc[hh][3] = fmaf(va.w, a, acc[hh][3]);
            }
        }
        #pragma unroll
        for (int hh = 0; hh < 8; hh++) {
            float4 o = {acc[hh][0], acc[hh][1], acc[hh][2], acc[hh][3]};
            *(float4*)&x1[((size_t)b*Nn + (size_t)(pi*32 + h0+hh)*Ww + gw)*Cc + half*256 + cl] = o;
        }
    }
}

__global__ __launch_bounds__(256) void cc_outW(
    const float* __restrict__ v_t, const float* __restrict__ att,
    float* __restrict__ x1)
{
    __shared__ float Vs[32][256];
    __shared__ float At[32][33];
    const int h = blockIdx.x, p = blockIdx.y;
    const int b = p >> 4, pi = (p >> 2) & 3, pj = p & 3;
    const int gh = pi*32 + h;
    const size_t rowpos = (size_t)b*Nn + (size_t)gh*Ww + pj*32;
    const int t = threadIdx.x;
    {
        const int wl = t >> 3, g0 = (t & 7) * 4;
        const float* arow = att + (((size_t)p*32 + h)*32 + wl)*64 + 32 + g0;
        float4 a = *(const float4*)arow;
        At[g0][wl]=a.x; At[g0+1][wl]=a.y; At[g0+2][wl]=a.z; At[g0+3][wl]=a.w;
    }
    const int s  = t & 63, wg = t >> 6;
    const int cl = s * 4, w0 = wg * 8;
    for (int half = 0; half < 2; half++) {
        __syncthreads();
        {
            const int g = t >> 3, c0 = (t & 7) * 32;
            const float* src = v_t + (rowpos + g)*Cc + half*256 + c0;
            #pragma unroll
            for (int u = 0; u < 32; u += 4)
                *(float4*)&Vs[g][c0+u] = *(const float4*)&src[u];
        }
        __syncthreads();
        float acc[8][4];
        #pragma unroll
        for (int i = 0; i < 8; i++) { acc[i][0]=0.f; acc[i][1]=0.f; acc[i][2]=0.f; acc[i][3]=0.f; }
        #pragma unroll 4
        for (int g = 0; g < 32; g++) {
            const float4 va = *(const float4*)&Vs[g][cl];
            #pragma unroll
            for (int ww = 0; ww < 8; ww++) {
                const float a = At[g][w0+ww];
                acc[ww][0] = fmaf(va.x, a, acc[ww][0]);
                acc[ww][1] = fmaf(va.y, a, acc[ww][1]);
                acc[ww][2] = fmaf(va.z, a, acc[ww][2]);
                acc[ww][3] = fmaf(va.w, a, acc[ww][3]);
            }
        }
        #pragma unroll
        for (int ww = 0; ww < 8; ww++) {
            float* op = x1 + (rowpos + w0+ww)*Cc + half*256 + cl;
            float4 r = *(const float4*)op;
            r.x += acc[ww][0]; r.y += acc[ww][1]; r.z += acc[ww][2]; r.w += acc[ww][3];
            *(float4*)op = r;
        }
    }
}

__global__ void zero_kernel(float* __restrict__ p, int n)
{
    const int i = blockIdx.x * 256 + threadIdx.x;
    if (i < n) p[i] = 0.f;
}

__global__ __launch_bounds__(256) void cam_normacc(
    const float* __restrict__ x1, float* __restrict__ nf2)
{
    const int b = blockIdx.x >> 6, ch = blockIdx.x & 63;
    const int t = threadIdx.x;
    const float* base = x1 + ((size_t)b*Nn + (size_t)ch*256)*Cc;
    float s0 = 0.f, s1 = 0.f;
    #pragma unroll 8
    for (int r = 0; r < 256; r++) {
        const float v0 = base[(size_t)r*Cc + t];
        const float v1 = base[(size_t)r*Cc + t + 256];
        s0 = fmaf(v0, v0, s0);
        s1 = fmaf(v1, v1, s1);
    }
    atomicAdd(&nf2[b*Cc + t],       s0);
    atomicAdd(&nf2[b*Cc + t + 256], s1);
}

__global__ __launch_bounds__(256) void cam_softmax(
    const float* __restrict__ Gp, const float* __restrict__ nf2,
    float* __restrict__ P)
{
    const int b = blockIdx.x >> 9, i = blockIdx.x & 511;
    const int t = threadIdx.x;
    __shared__ float red[8];
    const size_t roff = ((size_t)b*512 + i) * 512;
    float v0 = 0.f, v1 = 0.f;
    #pragma unroll
    for (int kc = 0; kc < 8; kc++) {
        const float* gp = Gp + (size_t)(kc*4 + b)*512*512 + (size_t)i*512;
        v0 += gp[t];
        v1 += gp[t + 256];
    }
    const float nfi = sqrtf(nf2[b*512 + i]) + EPSf;
    const float nj0 = sqrtf(nf2[b*512 + t]) + EPSf;
    const float nj1 = sqrtf(nf2[b*512 + t + 256]) + EPSf;
    float e0 = v0 / (nfi*nj0), e1 = v1 / (nfi*nj1);
    float m = fmaxf(e0, e1);
    #pragma unroll
    for (int o = 32; o > 0; o >>= 1) m = fmaxf(m, __shfl_xor(m, o, 64));
    if ((t & 63) == 0) red[t >> 6] = m;
    __syncthreads();
    m = fmaxf(fmaxf(red[0], red[1]), fmaxf(red[2], red[3]));
    float p0 = __expf(e0 - m), p1 = __expf(e1 - m);
    float s = p0 + p1;
    #pragma unroll
    for (int o = 32; o > 0; o >>= 1) s += __shfl_xor(s, o, 64);
    if ((t & 63) == 0) red[4 + (t >> 6)] = s;
    __syncthreads();
    s = red[4] + red[5] + red[6] + red[7];
    const float inv = 1.f / s;
    P[roff + t]       = p0 * inv;
    P[roff + t + 256] = p1 * inv;
}

// ===========================================================================
extern "C" void kernel_launch(void* const* d_in, const int* in_sizes, int n_in,
                              void* d_out, int out_size, void* d_ws, size_t ws_size,
                              hipStream_t stream)
{
    (void)in_sizes; (void)n_in; (void)out_size; (void)ws_size;
    const float* x    = (const float*)d_in[0];
    const float* wqp  = (const float*)d_in[1];
    const float* bqp  = (const float*)d_in[2];
    const float* wkp  = (const float*)d_in[3];
    const float* bkp  = (const float*)d_in[4];
    const float* wvp  = (const float*)d_in[5];
    const float* bvp  = (const float*)d_in[6];
    const float* gmp  = (const float*)d_in[7];
    float* out = (float*)d_out;

    char* W = (char*)d_ws;
    float* q_t = (float*)(W);                    //  33,554,432 B
    float* k_t = (float*)(W + 33554432);         //  33,554,432
    float* v_t = (float*)(W + 67108864);         // 134,217,728
    float* x1  = (float*)(W + 201326592);        // 134,217,728
    float* att = (float*)(W + 335544320);        //  16,777,216
    float* nq  = (float*)(W + 352321536);        //     262,144
    float* nk  = (float*)(W + 352583680);        //     262,144
    u16*   xh  = (u16*)  (W + 352845824);        //  67,108,864
    u16*   xl  = (u16*)  (W + 419954688);        //  67,108,864
    u16*   wh  = (u16*)  (W + 487063552);        //     786,432
    u16*   wl  = (u16*)  (W + 487849984);        //     786,432
    float* bcat= (float*)(W + 488636416);        //       3,072  (end ~489 MB)
    // CAM-phase aliases (q_t/k_t dead after iteration-2 energies):
    float* nf2 = q_t;                                            //   8 KB
    float* Gp  = (float*)(W + 16384);                            //  32 MB
    float* P   = (float*)(W + 16384 + 33554432);                 //   4 MB
    u16*   Ph  = (u16*)  (W + 16384 + 33554432 + 4194304);       //   2 MB
    u16*   Pl  = (u16*)  (W + 16384 + 33554432 + 4194304 + 2097152);
    // fT aliases v_t (dead after iteration-2 cc_out):
    u16*   fTh = (u16*)(W + 67108864);                           //  67 MB
    u16*   fTl = (u16*)(W + 67108864 + 67108864);                //  67 MB

    conv_w  <<<dim3(768),      256, 0, stream>>>(wqp,bqp, wkp,bkp, wvp,bvp, wh, wl, bcat);
    conv_x_t<<<dim3(256,8,4),  256, 0, stream>>>(x, xh, xl);

    for (int it = 0; it < 2; it++) {
        if (it == 1)
            conv_cl<<<dim3(16384), 256, 0, stream>>>(x1, xh, xl, (long)Bn*Nn*Cc);
        qkv_mfma <<<dim3(128,6,4), 256, 0, stream>>>(xh, xl, wh, wl, bcat, q_t, k_t, v_t);
        qk_norms <<<dim3(256),     256, 0, stream>>>(q_t, k_t, nq, nk);
        energy_H <<<dim3(32,64),   256, 0, stream>>>(q_t, k_t, nq, nk, att);
        energy_W <<<dim3(32,64),   256, 0, stream>>>(q_t, k_t, nq, nk, att);
        softmax64<<<dim3(256),     256, 0, stream>>>(att);
        cc_outH  <<<dim3(32,64),   256, 0, stream>>>(v_t, att, x1);
        cc_outW  <<<dim3(32,64),   256, 0, stream>>>(v_t, att, x1);
    }

    // CAM
    conv_cl   <<<dim3(16384),   256, 0, stream>>>(x1, xh, xl, (long)Bn*Nn*Cc);
    conv_t_cl <<<dim3(256,8,4), 256, 0, stream>>>(x1, fTh, fTl);
    zero_kernel<<<dim3(8),      256, 0, stream>>>(nf2, 2048);
    cam_normacc<<<dim3(256),    256, 0, stream>>>(x1, nf2);
    gram_mfma <<<dim3(4,4,32),  256, 0, stream>>>(fTh, fTl, Gp);
    cam_softmax<<<dim3(2048),   256, 0, stream>>>(Gp, nf2, P);
    conv_cl   <<<dim3(512),     256, 0, stream>>>(P, Ph, Pl, (long)Bn*512*512);
    camout_mfma<<<dim3(128,4,4),256, 0, stream>>>(Ph, Pl, xh, xl, fTh, fTl, gmp, out);
}

// Round 8
// 1373.686 us; speedup vs baseline: 1.8188x; 1.0684x over previous
//
#include <hip/hip_runtime.h>
#include <math.h>

// Problem constants (shapes fixed by reference setup_inputs)
constexpr int Bn = 4;
constexpr int Cc = 512;
constexpr int CQ = 128;
constexpr int Hh = 128, Ww = 128;
constexpr int Nn = Hh * Ww;        // 16384
constexpr int NPATCH = 64;         // B * 4 * 4
constexpr float EPSf = 1e-10f;

typedef unsigned int u32;
typedef unsigned short u16;
typedef __attribute__((ext_vector_type(8))) short bf16x8;
typedef __attribute__((ext_vector_type(4))) float f32x4;

__device__ inline u16 f2bf(float f) {
    u32 u = __float_as_uint(f);
    u32 r = u + 0x7fffu + ((u >> 16) & 1u);
    return (u16)(r >> 16);
}
__device__ inline float bf2f(u16 h) { return __uint_as_float((u32)h << 16); }

#define GLOAD16(g, l) __builtin_amdgcn_global_load_lds( \
    (const __attribute__((address_space(1))) u32*)(g), \
    (__attribute__((address_space(3))) u32*)(l), 16, 0, 0)

// ===========================================================================
// Converters
// ===========================================================================

// weights: wq[128][512], wk[128][512], wv[512][512] -> wh/wl [768][512], bcat[768]
__global__ __launch_bounds__(256) void conv_w(
    const float* __restrict__ wq, const float* __restrict__ bq,
    const float* __restrict__ wk, const float* __restrict__ bk,
    const float* __restrict__ wv, const float* __restrict__ bv,
    u16* __restrict__ wh, u16* __restrict__ wl, float* __restrict__ bcat)
{
    const int oc = blockIdx.x;  // 0..767
    const float* src; float bias;
    if (oc < 128)      { src = wq + (size_t)oc * 512;        bias = bq[oc]; }
    else if (oc < 256) { src = wk + (size_t)(oc-128) * 512;  bias = bk[oc-128]; }
    else               { src = wv + (size_t)(oc-256) * 512;  bias = bv[oc-256]; }
    for (int c = threadIdx.x; c < 512; c += 256) {
        float v = src[c];
        u16 h = f2bf(v);
        wh[(size_t)oc*512 + c] = h;
        wl[(size_t)oc*512 + c] = f2bf(v - bf2f(h));
    }
    if (threadIdx.x == 0) bcat[oc] = bias;
}

// x [b][C][N] fp32 -> xh/xl channel-last [(b,n)][C] bf16 (transpose-convert)
__global__ __launch_bounds__(256) void conv_x_t(
    const float* __restrict__ x, u16* __restrict__ xh, u16* __restrict__ xl)
{
    __shared__ float T[64][65];
    const int n0 = blockIdx.x * 64, c0 = blockIdx.y * 64, b = blockIdx.z;
    const int t = threadIdx.x;
    {
        const int cc = t >> 2, nn = (t & 3) * 16;
        const float* s = x + ((size_t)b*Cc + c0 + cc)*Nn + n0 + nn;
        #pragma unroll
        for (int u = 0; u < 16; u += 4) {
            float4 v = *(const float4*)(s + u);
            T[cc][nn+u]=v.x; T[cc][nn+u+1]=v.y; T[cc][nn+u+2]=v.z; T[cc][nn+u+3]=v.w;
        }
    }
    __syncthreads();
    {
        const int nn = t >> 2, cc0 = (t & 3) * 16;
        u16 hs[16] __attribute__((aligned(16)));
        u16 ls[16] __attribute__((aligned(16)));
        #pragma unroll
        for (int e = 0; e < 16; e++) {
            float v = T[cc0+e][nn];
            u16 h = f2bf(v);
            hs[e] = h; ls[e] = f2bf(v - bf2f(h));
        }
        const size_t o = ((size_t)b*Nn + n0 + nn)*Cc + c0 + cc0;
        *(uint4*)&xh[o]   = *(const uint4*)&hs[0];
        *(uint4*)&xh[o+8] = *(const uint4*)&hs[8];
        *(uint4*)&xl[o]   = *(const uint4*)&ls[0];
        *(uint4*)&xl[o+8] = *(const uint4*)&ls[8];
    }
}

// flat fp32 -> hi/lo bf16 (no transpose) — used only for P
__global__ __launch_bounds__(256) void conv_cl(
    const float* __restrict__ s, u16* __restrict__ h, u16* __restrict__ l, long n)
{
    const long i = (((long)blockIdx.x << 8) + threadIdx.x) << 3;
    if (i >= n) return;
    float4 a = *(const float4*)(s + i), b4 = *(const float4*)(s + i + 4);
    float v[8] = {a.x,a.y,a.z,a.w,b4.x,b4.y,b4.z,b4.w};
    u16 hs[8] __attribute__((aligned(16)));
    u16 ls[8] __attribute__((aligned(16)));
    #pragma unroll
    for (int e = 0; e < 8; e++) {
        u16 hh = f2bf(v[e]);
        hs[e] = hh; ls[e] = f2bf(v[e] - bf2f(hh));
    }
    *(uint4*)&h[i] = *(const uint4*)hs;
    *(uint4*)&l[i] = *(const uint4*)ls;
}

// x1h/x1l channel-last [(b,n)][C] -> fTh/fTl [b][C][N] (u16 LDS transpose)
__global__ __launch_bounds__(256) void conv_t_cl(
    const u16* __restrict__ x1h, const u16* __restrict__ x1l,
    u16* __restrict__ th, u16* __restrict__ tl)
{
    __shared__ u16 Th[64][72], Tl[64][72];   // 72 pad: 144B rows, 16B-aligned vec ops
    const int n0 = blockIdx.x * 64, c0 = blockIdx.y * 64, b = blockIdx.z;
    const int t = threadIdx.x;
    {
        const int nn = t >> 2, cc0 = (t & 3) * 16;
        const size_t src = ((size_t)b*Nn + n0 + nn)*Cc + c0 + cc0;
        *(uint4*)&Th[nn][cc0]     = *(const uint4*)&x1h[src];
        *(uint4*)&Th[nn][cc0 + 8] = *(const uint4*)&x1h[src + 8];
        *(uint4*)&Tl[nn][cc0]     = *(const uint4*)&x1l[src];
        *(uint4*)&Tl[nn][cc0 + 8] = *(const uint4*)&x1l[src + 8];
    }
    __syncthreads();
    {
        const int cc = t >> 2, nn0 = (t & 3) * 16;
        u16 hs[16] __attribute__((aligned(16)));
        u16 ls[16] __attribute__((aligned(16)));
        #pragma unroll
        for (int e = 0; e < 16; e++) { hs[e] = Th[nn0+e][cc]; ls[e] = Tl[nn0+e][cc]; }
        const size_t o = ((size_t)b*Cc + c0 + cc)*Nn + n0 + nn0;
        *(uint4*)&th[o]   = *(const uint4*)&hs[0];
        *(uint4*)&th[o+8] = *(const uint4*)&hs[8];
        *(uint4*)&tl[o]   = *(const uint4*)&ls[0];
        *(uint4*)&tl[o+8] = *(const uint4*)&ls[8];
    }
}

// ===========================================================================
// Split-bf16 MFMA GEMM kernels (validated r6: 0 bank conflicts, MfmaUtil ~35%)
// ===========================================================================

// Fused QKV: A = x channel-last hi/lo [(b,n)][512]; B = W [768][512] hi/lo.
__global__ __launch_bounds__(256) void qkv_mfma(
    const u16* __restrict__ xh, const u16* __restrict__ xl,
    const u16* __restrict__ wh, const u16* __restrict__ wl,
    const float* __restrict__ bcat,
    float* __restrict__ q_t, float* __restrict__ k_t, float* __restrict__ v_t)
{
    __shared__ char Ash[16384];
    __shared__ char Bsh[16384];
    const int t = threadIdx.x, lane = t & 63, wid = t >> 6;
    const int n0 = blockIdx.x * 128, oc0 = blockIdx.y * 128, b = blockIdx.z;
    const size_t bN = (size_t)b * Nn;

    float* outp; int ocb, OC;
    if (oc0 == 0)        { outp = q_t; ocb = 0;         OC = CQ; }
    else if (oc0 == 128) { outp = k_t; ocb = 0;         OC = CQ; }
    else                 { outp = v_t; ocb = oc0 - 256; OC = Cc; }

    const u16* sA[4]; const u16* sB[4];
    #pragma unroll
    for (int q = 0; q < 4; q++) {
        const int p = ((wid*4 + q) << 10) + lane*16;
        const int row = p >> 7;
        const int lchunk = ((p >> 4) & 7) ^ (row & 7);
        const int ko = (lchunk & 3) * 8;
        sA[q] = ((lchunk < 4) ? xh : xl) + (bN + n0 + row)*(size_t)Cc + ko;
        sB[q] = ((lchunk < 4) ? wh : wl) + (size_t)(oc0 + row)*Cc + ko;
    }

    const int wr = wid >> 1, wc = wid & 1;
    int aoff[4], boff[4];
    #pragma unroll
    for (int m = 0; m < 4; m++) {
        const int ra = (wr << 6) + (m << 4) + (lane & 15);
        aoff[m] = (ra << 7) + ((((lane >> 4) << 4)) ^ ((ra & 7) << 4));
        const int rb = (wc << 6) + (m << 4) + (lane & 15);
        boff[m] = (rb << 7) + ((((lane >> 4) << 4)) ^ ((rb & 7) << 4));
    }

    f32x4 acc[4][4];
    #pragma unroll
    for (int m = 0; m < 4; m++)
        #pragma unroll
        for (int n = 0; n < 4; n++) acc[m][n] = (f32x4){0.f, 0.f, 0.f, 0.f};

    for (int ks = 0; ks < 16; ks++) {
        if (ks) __syncthreads();
        #pragma unroll
        for (int q = 0; q < 4; q++) {
            GLOAD16(sA[q], Ash + ((wid*4 + q) << 10));
            GLOAD16(sB[q], Bsh + ((wid*4 + q) << 10));
            sA[q] += 32; sB[q] += 32;
        }
        __syncthreads();
        bf16x8 ah[4], al[4], bh[4], bl[4];
        #pragma unroll
        for (int m = 0; m < 4; m++) {
            ah[m] = *(const bf16x8*)(Ash + aoff[m]);
            al[m] = *(const bf16x8*)(Ash + (aoff[m] ^ 64));
            bh[m] = *(const bf16x8*)(Bsh + boff[m]);
            bl[m] = *(const bf16x8*)(Bsh + (boff[m] ^ 64));
        }
        #pragma unroll
        for (int m = 0; m < 4; m++)
            #pragma unroll
            for (int n = 0; n < 4; n++) {
                acc[m][n] = __builtin_amdgcn_mfma_f32_16x16x32_bf16(ah[m], bh[n], acc[m][n], 0, 0, 0);
                acc[m][n] = __builtin_amdgcn_mfma_f32_16x16x32_bf16(ah[m], bl[n], acc[m][n], 0, 0, 0);
                acc[m][n] = __builtin_amdgcn_mfma_f32_16x16x32_bf16(al[m], bh[n], acc[m][n], 0, 0, 0);
            }
    }

    const int col = lane & 15, rq = lane >> 4;
    #pragma unroll
    for (int n = 0; n < 4; n++) {
        const int oc = (wc << 6) + (n << 4) + col;
        const float bias = bcat[oc0 + oc];
        #pragma unroll
        for (int m = 0; m < 4; m++) {
            #pragma unroll
            for (int r = 0; r < 4; r++) {
                const int nrow = n0 + (wr << 6) + (m << 4) + (rq << 2) + r;
                outp[(bN + nrow)*OC + ocb + oc] = acc[m][n][r] + bias;
            }
        }
    }
}

// CAM Gram partials: A = B = fT [b][512][16384] hi/lo; split-K over 8 chunks.
__global__ __launch_bounds__(256) void gram_mfma(
    const u16* __restrict__ fTh, const u16* __restrict__ fTl,
    float* __restrict__ Gp)
{
    __shared__ char Ash[16384];
    __shared__ char Bsh[16384];
    const int t = threadIdx.x, lane = t & 63, wid = t >> 6;
    const int i0 = blockIdx.x * 128, j0 = blockIdx.y * 128;
    const int b = blockIdx.z >> 3, kc = blockIdx.z & 7;
    const size_t cb = (size_t)b * 512 * Nn;

    const u16* sA[4]; const u16* sB[4];
    #pragma unroll
    for (int q = 0; q < 4; q++) {
        const int p = ((wid*4 + q) << 10) + lane*16;
        const int row = p >> 7;
        const int lchunk = ((p >> 4) & 7) ^ (row & 7);
        const int ko = (lchunk & 3) * 8;
        const u16* s = (lchunk < 4) ? fTh : fTl;
        sA[q] = s + cb + (size_t)(i0 + row)*Nn + kc*2048 + ko;
        sB[q] = s + cb + (size_t)(j0 + row)*Nn + kc*2048 + ko;
    }

    const int wr = wid >> 1, wc = wid & 1;
    int aoff[4], boff[4];
    #pragma unroll
    for (int m = 0; m < 4; m++) {
        const int ra = (wr << 6) + (m << 4) + (lane & 15);
        aoff[m] = (ra << 7) + ((((lane >> 4) << 4)) ^ ((ra & 7) << 4));
        const int rb = (wc << 6) + (m << 4) + (lane & 15);
        boff[m] = (rb << 7) + ((((lane >> 4) << 4)) ^ ((rb & 7) << 4));
    }

    f32x4 acc[4][4];
    #pragma unroll
    for (int m = 0; m < 4; m++)
        #pragma unroll
        for (int n = 0; n < 4; n++) acc[m][n] = (f32x4){0.f, 0.f, 0.f, 0.f};

    for (int ks = 0; ks < 64; ks++) {
        if (ks) __syncthreads();
        #pragma unroll
        for (int q = 0; q < 4; q++) {
            GLOAD16(sA[q], Ash + ((wid*4 + q) << 10));
            GLOAD16(sB[q], Bsh + ((wid*4 + q) << 10));
            sA[q] += 32; sB[q] += 32;
        }
        __syncthreads();
        bf16x8 ah[4], al[4], bh[4], bl[4];
        #pragma unroll
        for (int m = 0; m < 4; m++) {
            ah[m] = *(const bf16x8*)(Ash + aoff[m]);
            al[m] = *(const bf16x8*)(Ash + (aoff[m] ^ 64));
            bh[m] = *(const bf16x8*)(Bsh + boff[m]);
            bl[m] = *(const bf16x8*)(Bsh + (boff[m] ^ 64));
        }
        #pragma unroll
        for (int m = 0; m < 4; m++)
            #pragma unroll
            for (int n = 0; n < 4; n++) {
                acc[m][n] = __builtin_amdgcn_mfma_f32_16x16x32_bf16(ah[m], bh[n], acc[m][n], 0, 0, 0);
                acc[m][n] = __builtin_amdgcn_mfma_f32_16x16x32_bf16(ah[m], bl[n], acc[m][n], 0, 0, 0);
                acc[m][n] = __builtin_amdgcn_mfma_f32_16x16x32_bf16(al[m], bh[n], acc[m][n], 0, 0, 0);
            }
    }

    float* gp = Gp + (size_t)(kc*4 + b) * 512 * 512;
    const int col = lane & 15, rq = lane >> 4;
    #pragma unroll
    for (int m = 0; m < 4; m++)
        #pragma unroll
        for (int r = 0; r < 4; r++) {
            const int ri = i0 + (wr << 6) + (m << 4) + (rq << 2) + r;
            #pragma unroll
            for (int n = 0; n < 4; n++)
                gp[(size_t)ri*512 + j0 + (wc << 6) + (n << 4) + col] = acc[m][n][r];
        }
}

// CAM out: A = P hi/lo; B = x1 channel-last hi/lo; residual fTh+fTl.
__global__ __launch_bounds__(256) void camout_mfma(
    const u16* __restrict__ Ph, const u16* __restrict__ Pl,
    const u16* __restrict__ x1h, const u16* __restrict__ x1l,
    const u16* __restrict__ fTh, const u16* __restrict__ fTl,
    const float* __restrict__ gamma, float* __restrict__ out)
{
    __shared__ char Ash[16384];
    __shared__ char Bsh[16384];
    const int t = threadIdx.x, lane = t & 63, wid = t >> 6;
    const int n0 = blockIdx.x * 128, i0 = blockIdx.y * 128, b = blockIdx.z;
    const size_t bN = (size_t)b * Nn;

    const u16* sA[4]; const u16* sB[4];
    #pragma unroll
    for (int q = 0; q < 4; q++) {
        const int p = ((wid*4 + q) << 10) + lane*16;
        const int row = p >> 7;
        const int lchunk = ((p >> 4) & 7) ^ (row & 7);
        const int ko = (lchunk & 3) * 8;
        sA[q] = ((lchunk < 4) ? Ph : Pl) + ((size_t)b*512 + i0 + row)*512 + ko;
        sB[q] = ((lchunk < 4) ? x1h : x1l) + (bN + n0 + row)*(size_t)Cc + ko;
    }

    const int wr = wid >> 1, wc = wid & 1;
    int aoff[4], boff[4];
    #pragma unroll
    for (int m = 0; m < 4; m++) {
        const int ra = (wr << 6) + (m << 4) + (lane & 15);
        aoff[m] = (ra << 7) + ((((lane >> 4) << 4)) ^ ((ra & 7) << 4));
        const int rb = (wc << 6) + (m << 4) + (lane & 15);
        boff[m] = (rb << 7) + ((((lane >> 4) << 4)) ^ ((rb & 7) << 4));
    }

    f32x4 acc[4][4];
    #pragma unroll
    for (int m = 0; m < 4; m++)
        #pragma unroll
        for (int n = 0; n < 4; n++) acc[m][n] = (f32x4){0.f, 0.f, 0.f, 0.f};

    for (int ks = 0; ks < 16; ks++) {
        if (ks) __syncthreads();
        #pragma unroll
        for (int q = 0; q < 4; q++) {
            GLOAD16(sA[q], Ash + ((wid*4 + q) << 10));
            GLOAD16(sB[q], Bsh + ((wid*4 + q) << 10));
            sA[q] += 32; sB[q] += 32;
        }
        __syncthreads();
        bf16x8 ah[4], al[4], bh[4], bl[4];
        #pragma unroll
        for (int m = 0; m < 4; m++) {
            ah[m] = *(const bf16x8*)(Ash + aoff[m]);
            al[m] = *(const bf16x8*)(Ash + (aoff[m] ^ 64));
            bh[m] = *(const bf16x8*)(Bsh + boff[m]);
            bl[m] = *(const bf16x8*)(Bsh + (boff[m] ^ 64));
        }
        #pragma unroll
        for (int m = 0; m < 4; m++)
            #pragma unroll
            for (int n = 0; n < 4; n++) {
                acc[m][n] = __builtin_amdgcn_mfma_f32_16x16x32_bf16(ah[m], bh[n], acc[m][n], 0, 0, 0);
                acc[m][n] = __builtin_amdgcn_mfma_f32_16x16x32_bf16(ah[m], bl[n], acc[m][n], 0, 0, 0);
                acc[m][n] = __builtin_amdgcn_mfma_f32_16x16x32_bf16(al[m], bh[n], acc[m][n], 0, 0, 0);
            }
    }

    const float gm = gamma[0];
    const int col = lane & 15, rq = lane >> 4;
    #pragma unroll
    for (int m = 0; m < 4; m++)
        #pragma unroll
        for (int r = 0; r < 4; r++) {
            const int i = i0 + (wr << 6) + (m << 4) + (rq << 2) + r;
            const size_t rb = ((size_t)b*512 + i)*Nn;
            #pragma unroll
            for (int n = 0; n < 4; n++) {
                const int nn = n0 + (wc << 6) + (n << 4) + col;
                const float res = bf2f(fTh[rb + nn]) + bf2f(fTl[rb + nn]);
                out[rb + nn] = fmaf(gm, acc[m][n][r], res);
            }
        }
}

// ===========================================================================
// CC attention: energies (norms fused in-block), softmax, apply (split-bf16 x1)
// ===========================================================================
__global__ __launch_bounds__(256) void energy_H(
    const float* __restrict__ q_t, const float* __restrict__ k_t,
    float* __restrict__ att)
{
    __shared__ float Qs[32][129], Ks[32][129];
    __shared__ float pq[32][8], pk[32][8];
    __shared__ float nqs[32], nks[32];
    const int w = blockIdx.x, p = blockIdx.y;
    const int b = p >> 4, pi = (p >> 2) & 3, pj = p & 3;
    const int gw = pj*32 + w;
    const int t = threadIdx.x;
    {
        const int h  = t >> 3;
        const int c0 = (t & 7) * 16;
        const size_t base = ((size_t)b*Nn + (size_t)(pi*32 + h)*Ww + gw) * CQ + c0;
        float sq = 0.f, sk = 0.f;
        #pragma unroll
        for (int u = 0; u < 16; u += 4) {
            float4 qa = *(const float4*)&q_t[base + u];
            float4 ka = *(const float4*)&k_t[base + u];
            Qs[h][c0+u]=qa.x; Qs[h][c0+u+1]=qa.y; Qs[h][c0+u+2]=qa.z; Qs[h][c0+u+3]=qa.w;
            Ks[h][c0+u]=ka.x; Ks[h][c0+u+1]=ka.y; Ks[h][c0+u+2]=ka.z; Ks[h][c0+u+3]=ka.w;
            sq += qa.x*qa.x + qa.y*qa.y + qa.z*qa.z + qa.w*qa.w;
            sk += ka.x*ka.x + ka.y*ka.y + ka.z*ka.z + ka.w*ka.w;
        }
        pq[h][t & 7] = sq; pk[h][t & 7] = sk;
    }
    __syncthreads();
    if (t < 32) {
        float s1 = 0.f, s2 = 0.f;
        #pragma unroll
        for (int j = 0; j < 8; j++) { s1 += pq[t][j]; s2 += pk[t][j]; }
        nqs[t] = sqrtf(s1) + EPSf; nks[t] = sqrtf(s2) + EPSf;
    }
    __syncthreads();
    const int h0 = (t & 15) * 2, g0 = (t >> 4) * 2;
    float a00=0,a01=0,a10=0,a11=0;
    #pragma unroll 4
    for (int c = 0; c < CQ; c++) {
        float q0 = Qs[h0][c], q1 = Qs[h0+1][c];
        float k0 = Ks[g0][c], k1 = Ks[g0+1][c];
        a00 = fmaf(q0,k0,a00); a01 = fmaf(q0,k1,a01);
        a10 = fmaf(q1,k0,a10); a11 = fmaf(q1,k1,a11);
    }
    const size_t ab = (((size_t)p*32 + h0)*32 + w)*64;
    att[ab + g0]            = a00 / (nqs[h0]   * nks[g0]);
    att[ab + g0 + 1]        = a01 / (nqs[h0]   * nks[g0+1]);
    att[ab + 2048 + g0]     = a10 / (nqs[h0+1] * nks[g0]);
    att[ab + 2048 + g0 + 1] = a11 / (nqs[h0+1] * nks[g0+1]);
}

__global__ __launch_bounds__(256) void energy_W(
    const float* __restrict__ q_t, const float* __restrict__ k_t,
    float* __restrict__ att)
{
    __shared__ float Qs[32][129], Ks[32][129];
    __shared__ float pq[32][8], pk[32][8];
    __shared__ float nqs[32], nks[32];
    const int h = blockIdx.x, p = blockIdx.y;
    const int b = p >> 4, pi = (p >> 2) & 3, pj = p & 3;
    const int gh = pi*32 + h;
    const size_t rowpos = (size_t)b*Nn + (size_t)gh*Ww + pj*32;
    const int t = threadIdx.x;
    {
        const int wl = t >> 3;
        const int c0 = (t & 7) * 16;
        const size_t base = (rowpos + wl) * CQ + c0;
        float sq = 0.f, sk = 0.f;
        #pragma unroll
        for (int u = 0; u < 16; u += 4) {
            float4 qa = *(const float4*)&q_t[base + u];
            float4 ka = *(const float4*)&k_t[base + u];
            Qs[wl][c0+u]=qa.x; Qs[wl][c0+u+1]=qa.y; Qs[wl][c0+u+2]=qa.z; Qs[wl][c0+u+3]=qa.w;
            Ks[wl][c0+u]=ka.x; Ks[wl][c0+u+1]=ka.y; Ks[wl][c0+u+2]=ka.z; Ks[wl][c0+u+3]=ka.w;
            sq += qa.x*qa.x + qa.y*qa.y + qa.z*qa.z + qa.w*qa.w;
            sk += ka.x*ka.x + ka.y*ka.y + ka.z*ka.z + ka.w*ka.w;
        }
        pq[wl][t & 7] = sq; pk[wl][t & 7] = sk;
    }
    __syncthreads();
    if (t < 32) {
        float s1 = 0.f, s2 = 0.f;
        #pragma unroll
        for (int j = 0; j < 8; j++) { s1 += pq[t][j]; s2 += pk[t][j]; }
        nqs[t] = sqrtf(s1) + EPSf; nks[t] = sqrtf(s2) + EPSf;
    }
    __syncthreads();
    const int w0 = (t & 15) * 2, g0 = (t >> 4) * 2;
    float a00=0,a01=0,a10=0,a11=0;
    #pragma unroll 4
    for (int c = 0; c < CQ; c++) {
        float q0 = Qs[w0][c], q1 = Qs[w0+1][c];
        float k0 = Ks[g0][c], k1 = Ks[g0+1][c];
        a00 = fmaf(q0,k0,a00); a01 = fmaf(q0,k1,a01);
        a10 = fmaf(q1,k0,a10); a11 = fmaf(q1,k1,a11);
    }
    const size_t ab = (((size_t)p*32 + h)*32 + w0)*64 + 32;
    att[ab + g0]          = a00 / (nqs[w0]   * nks[g0]);
    att[ab + g0 + 1]      = a01 / (nqs[w0]   * nks[g0+1]);
    att[ab + 64 + g0]     = a10 / (nqs[w0+1] * nks[g0]);
    att[ab + 64 + g0 + 1] = a11 / (nqs[w0+1] * nks[g0+1]);
}

__global__ __launch_bounds__(256) void softmax64(float* __restrict__ att)
{
    const size_t idx = (size_t)blockIdx.x * 256 + threadIdx.x;
    float* row = att + idx * 64;
    float v[64];
    float m = -1e30f;
    #pragma unroll
    for (int i = 0; i < 64; i += 4) {
        float4 x4 = *(const float4*)&row[i];
        v[i]=x4.x; v[i+1]=x4.y; v[i+2]=x4.z; v[i+3]=x4.w;
        m = fmaxf(m, fmaxf(fmaxf(x4.x,x4.y), fmaxf(x4.z,x4.w)));
    }
    float s = 0.f;
    #pragma unroll
    for (int i = 0; i < 64; i++) { v[i] = __expf(v[i] - m); s += v[i]; }
    const float inv = 1.f / s;
    #pragma unroll
    for (int i = 0; i < 64; i += 4) {
        float4 x4 = {v[i]*inv, v[i+1]*inv, v[i+2]*inv, v[i+3]*inv};
        *(float4*)&row[i] = x4;
    }
}

// outH: writes x1h/x1l ('=' split write)
__global__ __launch_bounds__(256) void cc_outH(
    const float* __restrict__ v_t, const float* __restrict__ att,
    u16* __restrict__ x1h, u16* __restrict__ x1l)
{
    __shared__ float Vs[32][256];
    __shared__ float At[32][33];
    const int w = blockIdx.x, p = blockIdx.y;
    const int b = p >> 4, pi = (p >> 2) & 3, pj = p & 3;
    const int gw = pj*32 + w;
    const int t = threadIdx.x;
    {
        const int hh = t >> 3, g0 = (t & 7) * 4;
        const float* arow = att + (((size_t)p*32 + hh)*32 + w)*64 + g0;
        float4 a = *(const float4*)arow;
        At[g0][hh]=a.x; At[g0+1][hh]=a.y; At[g0+2][hh]=a.z; At[g0+3][hh]=a.w;
    }
    const int s  = t & 63, hg = t >> 6;
    const int cl = s * 4, h0 = hg * 8;
    for (int half = 0; half < 2; half++) {
        __syncthreads();
        {
            const int g = t >> 3, c0 = (t & 7) * 32;
            const float* src = v_t + ((size_t)b*Nn + (size_t)(pi*32 + g)*Ww + gw)*Cc + half*256 + c0;
            #pragma unroll
            for (int u = 0; u < 32; u += 4)
                *(float4*)&Vs[g][c0+u] = *(const float4*)&src[u];
        }
        __syncthreads();
        float acc[8][4];
        #pragma unroll
        for (int i = 0; i < 8; i++) { acc[i][0]=0.f; acc[i][1]=0.f; acc[i][2]=0.f; acc[i][3]=0.f; }
        #pragma unroll 4
        for (int g = 0; g < 32; g++) {
            const float4 va = *(const float4*)&Vs[g][cl];
            #pragma unroll
            for (int hh = 0; hh < 8; hh++) {
                const float a = At[g][h0+hh];
                acc[hh][0] = fmaf(va.x, a, acc[hh][0]);
                acc[hh][1] = fmaf(va.y, a, acc[hh][1]);
                acc[hh][2] = fmaf(va.z, a, acc[hh][2]);
                acc[hh][3] = fmaf(va.w, a, acc[hh][3]);
            }
        }
        #pragma unroll
        for (int hh = 0; hh < 8; hh++) {
            u16 hs[4] __attribute__((aligned(8)));
            u16 ls[4] __attribute__((aligned(8)));
            #pragma unroll
            for (int j = 0; j < 4; j++) {
                const float v = acc[hh][j];
                const u16 h2 = f2bf(v);
                hs[j] = h2; ls[j] = f2bf(v - bf2f(h2));
            }
            const size_t o = ((size_t)b*Nn + (size_t)(pi*32 + h0+hh)*Ww + gw)*Cc + half*256 + cl;
            *(uint2*)&x1h[o] = *(const uint2*)hs;
            *(uint2*)&x1l[o] = *(const uint2*)ls;
        }
    }
}

// outW: read-modify-write on x1h/x1l (reconstruct, add, re-split)
__global__ __launch_bounds__(256) void cc_outW(
    const float* __restrict__ v_t, const float* __restrict__ att,
    u16* __restrict__ x1h, u16* __restrict__ x1l)
{
    __shared__ float Vs[32][256];
    __shared__ float At[32][33];
    const int h = blockIdx.x, p = blockIdx.y;
    const int b = p >> 4, pi = (p >> 2) & 3, pj = p & 3;
    const int gh = pi*32 + h;
    const size_t rowpos = (size_t)b*Nn + (size_t)gh*Ww + pj*32;
    const int t = threadIdx.x;
    {
        const int wl = t >> 3, g0 = (t & 7) * 4;
        const float* arow = att + (((size_t)p*32 + h)*32 + wl)*64 + 32 + g0;
        float4 a = *(const float4*)arow;
        At[g0][wl]=a.x; At[g0+1][wl]=a.y; At[g0+2][wl]=a.z; At[g0+3][wl]=a.w;
    }
    const int s  = t & 63, wg = t >> 6;
    const int cl = s * 4, w0 = wg * 8;
    for (int half = 0; half < 2; half++) {
        __syncthreads();
        {
            const int g = t >> 3, c0 = (t & 7) * 32;
            const float* src = v_t + (rowpos + g)*Cc + half*256 + c0;
            #pragma unroll
            for (int u = 0; u < 32; u += 4)
                *(float4*)&Vs[g][c0+u] = *(const float4*)&src[u];
        }
        __syncthreads();
        float acc[8][4];
        #pragma unroll
        for (int i = 0; i < 8; i++) { acc[i][0]=0.f; acc[i][1]=0.f; acc[i][2]=0.f; acc[i][3]=0.f; }
        #pragma unroll 4
        for (int g = 0; g < 32; g++) {
            const float4 va = *(const float4*)&Vs[g][cl];
            #pragma unroll
            for (int ww = 0; ww < 8; ww++) {
                const float a = At[g][w0+ww];
                acc[ww][0] = fmaf(va.x, a, acc[ww][0]);
                acc[ww][1] = fmaf(va.y, a, acc[ww][1]);
                acc[ww][2] = fmaf(va.z, a, acc[ww][2]);
                acc[ww][3] = fmaf(va.w, a, acc[ww][3]);
            }
        }
        #pragma unroll
        for (int ww = 0; ww < 8; ww++) {
            const size_t o = (rowpos + w0+ww)*Cc + half*256 + cl;
            const uint2 ph = *(const uint2*)&x1h[o];
            const uint2 pl = *(const uint2*)&x1l[o];
            float v[4];
            v[0] = bf2f((u16)ph.x)        + bf2f((u16)pl.x)        + acc[ww][0];
            v[1] = bf2f((u16)(ph.x>>16))  + bf2f((u16)(pl.x>>16))  + acc[ww][1];
            v[2] = bf2f((u16)ph.y)        + bf2f((u16)pl.y)        + acc[ww][2];
            v[3] = bf2f((u16)(ph.y>>16))  + bf2f((u16)(pl.y>>16))  + acc[ww][3];
            u16 hs[4] __attribute__((aligned(8)));
            u16 ls[4] __attribute__((aligned(8)));
            #pragma unroll
            for (int j = 0; j < 4; j++) {
                const u16 h2 = f2bf(v[j]);
                hs[j] = h2; ls[j] = f2bf(v[j] - bf2f(h2));
            }
            *(uint2*)&x1h[o] = *(const uint2*)hs;
            *(uint2*)&x1l[o] = *(const uint2*)ls;
        }
    }
}

// ===========================================================================
// CAM small kernels
// ===========================================================================
// block-per-channel norm² from fT rows (contiguous) — no atomics
__global__ __launch_bounds__(256) void cam_normacc(
    const u16* __restrict__ fTh, const u16* __restrict__ fTl, float* __restrict__ nf2)
{
    const int bc = blockIdx.x;             // b*512 + ch
    const u16* ph = fTh + (size_t)bc * Nn;
    const u16* pl = fTl + (size_t)bc * Nn;
    const int t = threadIdx.x;
    float s = 0.f;
    #pragma unroll
    for (int base = 0; base < Nn; base += 2048) {
        const int i = base + t*8;
        const uint4 hv = *(const uint4*)&ph[i];
        const uint4 lv = *(const uint4*)&pl[i];
        const u32 hw[4] = {hv.x, hv.y, hv.z, hv.w};
        const u32 lw[4] = {lv.x, lv.y, lv.z, lv.w};
        #pragma unroll
        for (int j = 0; j < 4; j++) {
            const float a  = bf2f((u16)hw[j])       + bf2f((u16)lw[j]);
            const float b2 = bf2f((u16)(hw[j]>>16)) + bf2f((u16)(lw[j]>>16));
            s = fmaf(a, a, s); s = fmaf(b2, b2, s);
        }
    }
    #pragma unroll
    for (int o = 32; o > 0; o >>= 1) s += __shfl_xor(s, o, 64);
    __shared__ float red[4];
    if ((t & 63) == 0) red[t >> 6] = s;
    __syncthreads();
    if (t == 0) nf2[bc] = red[0] + red[1] + red[2] + red[3];
}

__global__ __launch_bounds__(256) void cam_softmax(
    const float* __restrict__ Gp, const float* __restrict__ nf2,
    float* __restrict__ P)
{
    const int b = blockIdx.x >> 9, i = blockIdx.x & 511;
    const int t = threadIdx.x;
    __shared__ float red[8];
    const size_t roff = ((size_t)b*512 + i) * 512;
    float v0 = 0.f, v1 = 0.f;
    #pragma unroll
    for (int kc = 0; kc < 8; kc++) {
        const float* gp = Gp + (size_t)(kc*4 + b)*512*512 + (size_t)i*512;
        v0 += gp[t];
        v1 += gp[t + 256];
    }
    const float nfi = sqrtf(nf2[b*512 + i]) + EPSf;
    const float nj0 = sqrtf(nf2[b*512 + t]) + EPSf;
    const float nj1 = sqrtf(nf2[b*512 + t + 256]) + EPSf;
    float e0 = v0 / (nfi*nj0), e1 = v1 / (nfi*nj1);
    float m = fmaxf(e0, e1);
    #pragma unroll
    for (int o = 32; o > 0; o >>= 1) m = fmaxf(m, __shfl_xor(m, o, 64));
    if ((t & 63) == 0) red[t >> 6] = m;
    __syncthreads();
    m = fmaxf(fmaxf(red[0], red[1]), fmaxf(red[2], red[3]));
    float p0 = __expf(e0 - m), p1 = __expf(e1 - m);
    float s = p0 + p1;
    #pragma unroll
    for (int o = 32; o > 0; o >>= 1) s += __shfl_xor(s, o, 64);
    if ((t & 63) == 0) red[4 + (t >> 6)] = s;
    __syncthreads();
    s = red[4] + red[5] + red[6] + red[7];
    const float inv = 1.f / s;
    P[roff + t]       = p0 * inv;
    P[roff + t + 256] = p1 * inv;
}

// ===========================================================================
extern "C" void kernel_launch(void* const* d_in, const int* in_sizes, int n_in,
                              void* d_out, int out_size, void* d_ws, size_t ws_size,
                              hipStream_t stream)
{
    (void)in_sizes; (void)n_in; (void)out_size; (void)ws_size;
    const float* x    = (const float*)d_in[0];
    const float* wqp  = (const float*)d_in[1];
    const float* bqp  = (const float*)d_in[2];
    const float* wkp  = (const float*)d_in[3];
    const float* bkp  = (const float*)d_in[4];
    const float* wvp  = (const float*)d_in[5];
    const float* bvp  = (const float*)d_in[6];
    const float* gmp  = (const float*)d_in[7];
    float* out = (float*)d_out;

    char* W = (char*)d_ws;
    float* q_t = (float*)(W);                    //  33,554,432 B
    float* k_t = (float*)(W + 33554432);         //  33,554,432
    float* v_t = (float*)(W + 67108864);         // 134,217,728
    u16*   x1h = (u16*)  (W + 201326592);        //  67,108,864
    u16*   x1l = (u16*)  (W + 268435456);        //  67,108,864
    float* att = (float*)(W + 335544320);        //  16,777,216
    u16*   xh  = (u16*)  (W + 352321536);        //  67,108,864
    u16*   xl  = (u16*)  (W + 419430400);        //  67,108,864
    u16*   wh  = (u16*)  (W + 486539264);        //     786,432
    u16*   wl  = (u16*)  (W + 487325696);        //     786,432
    float* bcat= (float*)(W + 488112128);        //       3,072  (end ~488 MB, < r6's proven 489)
    // CAM scratch aliases dead q_t/k_t region (67 MB):
    float* nf2 = (float*)(W);                                    //   8 KB
    float* Gp  = (float*)(W + 16384);                            //  32 MB
    float* P   = (float*)(W + 16384 + 33554432);                 //   4 MB
    u16*   Ph  = (u16*)  (W + 16384 + 33554432 + 4194304);       //   2 MB
    u16*   Pl  = (u16*)  (W + 16384 + 33554432 + 4194304 + 2097152);
    // fT aliases v_t (dead after iteration-2 cc_out):
    u16*   fTh = (u16*)(W + 67108864);                           //  67 MB
    u16*   fTl = (u16*)(W + 134217728);                          //  67 MB

    conv_w  <<<dim3(768),      256, 0, stream>>>(wqp,bqp, wkp,bkp, wvp,bvp, wh, wl, bcat);
    conv_x_t<<<dim3(256,8,4),  256, 0, stream>>>(x, xh, xl);

    for (int it = 0; it < 2; it++) {
        const u16* ah = (it == 0) ? xh : x1h;
        const u16* al = (it == 0) ? xl : x1l;
        qkv_mfma <<<dim3(128,6,4), 256, 0, stream>>>(ah, al, wh, wl, bcat, q_t, k_t, v_t);
        energy_H <<<dim3(32,64),   256, 0, stream>>>(q_t, k_t, att);
        energy_W <<<dim3(32,64),   256, 0, stream>>>(q_t, k_t, att);
        softmax64<<<dim3(256),     256, 0, stream>>>(att);
        cc_outH  <<<dim3(32,64),   256, 0, stream>>>(v_t, att, x1h, x1l);
        cc_outW  <<<dim3(32,64),   256, 0, stream>>>(v_t, att, x1h, x1l);
    }

    // CAM
    conv_t_cl  <<<dim3(256,8,4), 256, 0, stream>>>(x1h, x1l, fTh, fTl);
    cam_normacc<<<dim3(2048),    256, 0, stream>>>(fTh, fTl, nf2);
    gram_mfma  <<<dim3(4,4,32),  256, 0, stream>>>(fTh, fTl, Gp);
    cam_softmax<<<dim3(2048),    256, 0, stream>>>(Gp, nf2, P);
    conv_cl    <<<dim3(512),     256, 0, stream>>>(P, Ph, Pl, (long)Bn*512*512);
    camout_mfma<<<dim3(128,4,4), 256, 0, stream>>>(Ph, Pl, x1h, x1l, fTh, fTl, gmp, out);
}

// Round 10
// 1298.393 us; speedup vs baseline: 1.9243x; 1.0580x over previous
//
#include <hip/hip_runtime.h>
#include <math.h>

// Problem constants (shapes fixed by reference setup_inputs)
constexpr int Bn = 4;
constexpr int Cc = 512;
constexpr int CQ = 128;
constexpr int Hh = 128, Ww = 128;
constexpr int Nn = Hh * Ww;        // 16384
constexpr int NPATCH = 64;         // B * 4 * 4
constexpr float EPSf = 1e-10f;

typedef unsigned int u32;
typedef unsigned short u16;
typedef __attribute__((ext_vector_type(8))) short bf16x8;
typedef __attribute__((ext_vector_type(4))) float f32x4;

__device__ inline u16 f2bf(float f) {
    u32 u = __float_as_uint(f);
    u32 r = u + 0x7fffu + ((u >> 16) & 1u);
    return (u16)(r >> 16);
}
__device__ inline float bf2f(u16 h) { return __uint_as_float((u32)h << 16); }

#define GLOAD16(g, l) __builtin_amdgcn_global_load_lds( \
    (const __attribute__((address_space(1))) u32*)(g), \
    (__attribute__((address_space(3))) u32*)(l), 16, 0, 0)

// ===========================================================================
// Converters
// ===========================================================================

// weights: wq[128][512], wk[128][512], wv[512][512] -> wh/wl [768][512], bcat[768]
__global__ __launch_bounds__(256) void conv_w(
    const float* __restrict__ wq, const float* __restrict__ bq,
    const float* __restrict__ wk, const float* __restrict__ bk,
    const float* __restrict__ wv, const float* __restrict__ bv,
    u16* __restrict__ wh, u16* __restrict__ wl, float* __restrict__ bcat)
{
    const int oc = blockIdx.x;  // 0..767
    const float* src; float bias;
    if (oc < 128)      { src = wq + (size_t)oc * 512;        bias = bq[oc]; }
    else if (oc < 256) { src = wk + (size_t)(oc-128) * 512;  bias = bk[oc-128]; }
    else               { src = wv + (size_t)(oc-256) * 512;  bias = bv[oc-256]; }
    for (int c = threadIdx.x; c < 512; c += 256) {
        float v = src[c];
        u16 h = f2bf(v);
        wh[(size_t)oc*512 + c] = h;
        wl[(size_t)oc*512 + c] = f2bf(v - bf2f(h));
    }
    if (threadIdx.x == 0) bcat[oc] = bias;
}

// x [b][C][N] fp32 -> xh/xl channel-last [(b,n)][C] bf16 (transpose-convert)
__global__ __launch_bounds__(256) void conv_x_t(
    const float* __restrict__ x, u16* __restrict__ xh, u16* __restrict__ xl)
{
    __shared__ float T[64][65];
    const int n0 = blockIdx.x * 64, c0 = blockIdx.y * 64, b = blockIdx.z;
    const int t = threadIdx.x;
    {
        const int cc = t >> 2, nn = (t & 3) * 16;
        const float* s = x + ((size_t)b*Cc + c0 + cc)*Nn + n0 + nn;
        #pragma unroll
        for (int u = 0; u < 16; u += 4) {
            float4 v = *(const float4*)(s + u);
            T[cc][nn+u]=v.x; T[cc][nn+u+1]=v.y; T[cc][nn+u+2]=v.z; T[cc][nn+u+3]=v.w;
        }
    }
    __syncthreads();
    {
        const int nn = t >> 2, cc0 = (t & 3) * 16;
        u16 hs[16] __attribute__((aligned(16)));
        u16 ls[16] __attribute__((aligned(16)));
        #pragma unroll
        for (int e = 0; e < 16; e++) {
            float v = T[cc0+e][nn];
            u16 h = f2bf(v);
            hs[e] = h; ls[e] = f2bf(v - bf2f(h));
        }
        const size_t o = ((size_t)b*Nn + n0 + nn)*Cc + c0 + cc0;
        *(uint4*)&xh[o]   = *(const uint4*)&hs[0];
        *(uint4*)&xh[o+8] = *(const uint4*)&hs[8];
        *(uint4*)&xl[o]   = *(const uint4*)&ls[0];
        *(uint4*)&xl[o+8] = *(const uint4*)&ls[8];
    }
}

// flat fp32 -> hi/lo bf16 (no transpose) — used only for P
__global__ __launch_bounds__(256) void conv_cl(
    const float* __restrict__ s, u16* __restrict__ h, u16* __restrict__ l, long n)
{
    const long i = (((long)blockIdx.x << 8) + threadIdx.x) << 3;
    if (i >= n) return;
    float4 a = *(const float4*)(s + i), b4 = *(const float4*)(s + i + 4);
    float v[8] = {a.x,a.y,a.z,a.w,b4.x,b4.y,b4.z,b4.w};
    u16 hs[8] __attribute__((aligned(16)));
    u16 ls[8] __attribute__((aligned(16)));
    #pragma unroll
    for (int e = 0; e < 8; e++) {
        u16 hh = f2bf(v[e]);
        hs[e] = hh; ls[e] = f2bf(v[e] - bf2f(hh));
    }
    *(uint4*)&h[i] = *(const uint4*)hs;
    *(uint4*)&l[i] = *(const uint4*)ls;
}

// x1h/x1l channel-last [(b,n)][C] -> fTh/fTl [b][C][N] (u16 LDS transpose)
__global__ __launch_bounds__(256) void conv_t_cl(
    const u16* __restrict__ x1h, const u16* __restrict__ x1l,
    u16* __restrict__ th, u16* __restrict__ tl)
{
    __shared__ u16 Th[64][72], Tl[64][72];   // 72 pad: 144B rows, 16B-aligned vec ops
    const int n0 = blockIdx.x * 64, c0 = blockIdx.y * 64, b = blockIdx.z;
    const int t = threadIdx.x;
    {
        const int nn = t >> 2, cc0 = (t & 3) * 16;
        const size_t src = ((size_t)b*Nn + n0 + nn)*Cc + c0 + cc0;
        *(uint4*)&Th[nn][cc0]     = *(const uint4*)&x1h[src];
        *(uint4*)&Th[nn][cc0 + 8] = *(const uint4*)&x1h[src + 8];
        *(uint4*)&Tl[nn][cc0]     = *(const uint4*)&x1l[src];
        *(uint4*)&Tl[nn][cc0 + 8] = *(const uint4*)&x1l[src + 8];
    }
    __syncthreads();
    {
        const int cc = t >> 2, nn0 = (t & 3) * 16;
        u16 hs[16] __attribute__((aligned(16)));
        u16 ls[16] __attribute__((aligned(16)));
        #pragma unroll
        for (int e = 0; e < 16; e++) { hs[e] = Th[nn0+e][cc]; ls[e] = Tl[nn0+e][cc]; }
        const size_t o = ((size_t)b*Cc + c0 + cc)*Nn + n0 + nn0;
        *(uint4*)&th[o]   = *(const uint4*)&hs[0];
        *(uint4*)&th[o+8] = *(const uint4*)&hs[8];
        *(uint4*)&tl[o]   = *(const uint4*)&ls[0];
        *(uint4*)&tl[o+8] = *(const uint4*)&ls[8];
    }
}

// ===========================================================================
// Split-bf16 MFMA GEMM kernels (validated r6: 0 bank conflicts, MfmaUtil ~35%)
// ===========================================================================

// Fused QKV: A = x channel-last hi/lo [(b,n)][512]; B = W [768][512] hi/lo.
__global__ __launch_bounds__(256) void qkv_mfma(
    const u16* __restrict__ xh, const u16* __restrict__ xl,
    const u16* __restrict__ wh, const u16* __restrict__ wl,
    const float* __restrict__ bcat,
    float* __restrict__ q_t, float* __restrict__ k_t, float* __restrict__ v_t)
{
    __shared__ char Ash[16384];
    __shared__ char Bsh[16384];
    const int t = threadIdx.x, lane = t & 63, wid = t >> 6;
    const int n0 = blockIdx.x * 128, oc0 = blockIdx.y * 128, b = blockIdx.z;
    const size_t bN = (size_t)b * Nn;

    float* outp; int ocb, OC;
    if (oc0 == 0)        { outp = q_t; ocb = 0;         OC = CQ; }
    else if (oc0 == 128) { outp = k_t; ocb = 0;         OC = CQ; }
    else                 { outp = v_t; ocb = oc0 - 256; OC = Cc; }

    const u16* sA[4]; const u16* sB[4];
    #pragma unroll
    for (int q = 0; q < 4; q++) {
        const int p = ((wid*4 + q) << 10) + lane*16;
        const int row = p >> 7;
        const int lchunk = ((p >> 4) & 7) ^ (row & 7);
        const int ko = (lchunk & 3) * 8;
        sA[q] = ((lchunk < 4) ? xh : xl) + (bN + n0 + row)*(size_t)Cc + ko;
        sB[q] = ((lchunk < 4) ? wh : wl) + (size_t)(oc0 + row)*Cc + ko;
    }

    const int wr = wid >> 1, wc = wid & 1;
    int aoff[4], boff[4];
    #pragma unroll
    for (int m = 0; m < 4; m++) {
        const int ra = (wr << 6) + (m << 4) + (lane & 15);
        aoff[m] = (ra << 7) + ((((lane >> 4) << 4)) ^ ((ra & 7) << 4));
        const int rb = (wc << 6) + (m << 4) + (lane & 15);
        boff[m] = (rb << 7) + ((((lane >> 4) << 4)) ^ ((rb & 7) << 4));
    }

    f32x4 acc[4][4];
    #pragma unroll
    for (int m = 0; m < 4; m++)
        #pragma unroll
        for (int n = 0; n < 4; n++) acc[m][n] = (f32x4){0.f, 0.f, 0.f, 0.f};

    for (int ks = 0; ks < 16; ks++) {
        if (ks) __syncthreads();
        #pragma unroll
        for (int q = 0; q < 4; q++) {
            GLOAD16(sA[q], Ash + ((wid*4 + q) << 10));
            GLOAD16(sB[q], Bsh + ((wid*4 + q) << 10));
            sA[q] += 32; sB[q] += 32;
        }
        __syncthreads();
        bf16x8 ah[4], al[4], bh[4], bl[4];
        #pragma unroll
        for (int m = 0; m < 4; m++) {
            ah[m] = *(const bf16x8*)(Ash + aoff[m]);
            al[m] = *(const bf16x8*)(Ash + (aoff[m] ^ 64));
            bh[m] = *(const bf16x8*)(Bsh + boff[m]);
            bl[m] = *(const bf16x8*)(Bsh + (boff[m] ^ 64));
        }
        #pragma unroll
        for (int m = 0; m < 4; m++)
            #pragma unroll
            for (int n = 0; n < 4; n++) {
                acc[m][n] = __builtin_amdgcn_mfma_f32_16x16x32_bf16(ah[m], bh[n], acc[m][n], 0, 0, 0);
                acc[m][n] = __builtin_amdgcn_mfma_f32_16x16x32_bf16(ah[m], bl[n], acc[m][n], 0, 0, 0);
                acc[m][n] = __builtin_amdgcn_mfma_f32_16x16x32_bf16(al[m], bh[n], acc[m][n], 0, 0, 0);
            }
    }

    const int col = lane & 15, rq = lane >> 4;
    #pragma unroll
    for (int n = 0; n < 4; n++) {
        const int oc = (wc << 6) + (n << 4) + col;
        const float bias = bcat[oc0 + oc];
        #pragma unroll
        for (int m = 0; m < 4; m++) {
            #pragma unroll
            for (int r = 0; r < 4; r++) {
                const int nrow = n0 + (wr << 6) + (m << 4) + (rq << 2) + r;
                outp[(bN + nrow)*OC + ocb + oc] = acc[m][n][r] + bias;
            }
        }
    }
}

// CAM Gram partials: A = B = fT [b][512][16384] hi/lo; split-K over 8 chunks.
// r9: XCD-chunked flat grid (each XCD owns 4 (b,kc) chunks -> L2-resident
// 4MB panel set) + upper-triangle tiles with mirrored float4 writes (G = G^T).
__global__ __launch_bounds__(256) void gram_mfma(
    const u16* __restrict__ fTh, const u16* __restrict__ fTl,
    float* __restrict__ Gp)
{
    __shared__ char Ash[16384];
    __shared__ char Bsh[16384];
    const int t = threadIdx.x, lane = t & 63, wid = t >> 6;
    // flat f in [0,320): xcd = f&7 (round-robin ID->XCD), 40 slots per XCD,
    // 10 triangle tiles per (b,kc), 4 (b,kc) per XCD.
    const int f    = blockIdx.x;
    const int slot = f >> 3;
    const int zz   = (f & 7) * 4 + slot / 10;      // (b,kc) index 0..31
    const int ti   = slot - (slot / 10) * 10;      // triangle tile 0..9
    const int tr   = ti < 4 ? 0 : ti < 7 ? 1 : ti < 9 ? 2 : 3;
    const int tc   = ti - (tr == 0 ? 0 : tr == 1 ? 3 : tr == 2 ? 5 : 6);
    const int i0   = tr * 128, j0 = tc * 128;      // i0 <= j0
    const int b    = zz >> 3, kc = zz & 7;
    const size_t cb = (size_t)b * 512 * Nn;

    const u16* sA[4]; const u16* sB[4];
    #pragma unroll
    for (int q = 0; q < 4; q++) {
        const int p = ((wid*4 + q) << 10) + lane*16;
        const int row = p >> 7;
        const int lchunk = ((p >> 4) & 7) ^ (row & 7);
        const int ko = (lchunk & 3) * 8;
        const u16* s = (lchunk < 4) ? fTh : fTl;
        sA[q] = s + cb + (size_t)(i0 + row)*Nn + kc*2048 + ko;
        sB[q] = s + cb + (size_t)(j0 + row)*Nn + kc*2048 + ko;
    }

    const int wr = wid >> 1, wc = wid & 1;
    int aoff[4], boff[4];
    #pragma unroll
    for (int m = 0; m < 4; m++) {
        const int ra = (wr << 6) + (m << 4) + (lane & 15);
        aoff[m] = (ra << 7) + ((((lane >> 4) << 4)) ^ ((ra & 7) << 4));
        const int rb = (wc << 6) + (m << 4) + (lane & 15);
        boff[m] = (rb << 7) + ((((lane >> 4) << 4)) ^ ((rb & 7) << 4));
    }

    f32x4 acc[4][4];
    #pragma unroll
    for (int m = 0; m < 4; m++)
        #pragma unroll
        for (int n = 0; n < 4; n++) acc[m][n] = (f32x4){0.f, 0.f, 0.f, 0.f};

    for (int ks = 0; ks < 64; ks++) {
        if (ks) __syncthreads();
        #pragma unroll
        for (int q = 0; q < 4; q++) {
            GLOAD16(sA[q], Ash + ((wid*4 + q) << 10));
            GLOAD16(sB[q], Bsh + ((wid*4 + q) << 10));
            sA[q] += 32; sB[q] += 32;
        }
        __syncthreads();
        bf16x8 ah[4], al[4], bh[4], bl[4];
        #pragma unroll
        for (int m = 0; m < 4; m++) {
            ah[m] = *(const bf16x8*)(Ash + aoff[m]);
            al[m] = *(const bf16x8*)(Ash + (aoff[m] ^ 64));
            bh[m] = *(const bf16x8*)(Bsh + boff[m]);
            bl[m] = *(const bf16x8*)(Bsh + (boff[m] ^ 64));
        }
        #pragma unroll
        for (int m = 0; m < 4; m++)
            #pragma unroll
            for (int n = 0; n < 4; n++) {
                acc[m][n] = __builtin_amdgcn_mfma_f32_16x16x32_bf16(ah[m], bh[n], acc[m][n], 0, 0, 0);
                acc[m][n] = __builtin_amdgcn_mfma_f32_16x16x32_bf16(ah[m], bl[n], acc[m][n], 0, 0, 0);
                acc[m][n] = __builtin_amdgcn_mfma_f32_16x16x32_bf16(al[m], bh[n], acc[m][n], 0, 0, 0);
            }
    }

    float* gp = Gp + (size_t)(kc*4 + b) * 512 * 512;
    const int col = lane & 15, rq = lane >> 4;
    // direct write: G[i][j] tile
    #pragma unroll
    for (int m = 0; m < 4; m++)
        #pragma unroll
        for (int r = 0; r < 4; r++) {
            const int ri = i0 + (wr << 6) + (m << 4) + (rq << 2) + r;
            #pragma unroll
            for (int n = 0; n < 4; n++)
                gp[(size_t)ri*512 + j0 + (wc << 6) + (n << 4) + col] = acc[m][n][r];
        }
    // mirrored write: G[j][i] tile (r walks the row index -> contiguous float4)
    if (i0 != j0) {
        #pragma unroll
        for (int m = 0; m < 4; m++) {
            const int ri0 = i0 + (wr << 6) + (m << 4) + (rq << 2);
            #pragma unroll
            for (int n = 0; n < 4; n++) {
                const int cj = j0 + (wc << 6) + (n << 4) + col;
                float4 v = {acc[m][n][0], acc[m][n][1], acc[m][n][2], acc[m][n][3]};
                *(float4*)&gp[(size_t)cj*512 + ri0] = v;
            }
        }
    }
}

// CAM out: A = P hi/lo; B = x1 channel-last hi/lo; residual fTh+fTl.
__global__ __launch_bounds__(256) void camout_mfma(
    const u16* __restrict__ Ph, const u16* __restrict__ Pl,
    const u16* __restrict__ x1h, const u16* __restrict__ x1l,
    const u16* __restrict__ fTh, const u16* __restrict__ fTl,
    const float* __restrict__ gamma, float* __restrict__ out)
{
    __shared__ char Ash[16384];
    __shared__ char Bsh[16384];
    const int t = threadIdx.x, lane = t & 63, wid = t >> 6;
    const int n0 = blockIdx.x * 128, i0 = blockIdx.y * 128, b = blockIdx.z;
    const size_t bN = (size_t)b * Nn;

    const u16* sA[4]; const u16* sB[4];
    #pragma unroll
    for (int q = 0; q < 4; q++) {
        const int p = ((wid*4 + q) << 10) + lane*16;
        const int row = p >> 7;
        const int lchunk = ((p >> 4) & 7) ^ (row & 7);
        const int ko = (lchunk & 3) * 8;
        sA[q] = ((lchunk < 4) ? Ph : Pl) + ((size_t)b*512 + i0 + row)*512 + ko;
        sB[q] = ((lchunk < 4) ? x1h : x1l) + (bN + n0 + row)*(size_t)Cc + ko;
    }

    const int wr = wid >> 1, wc = wid & 1;
    int aoff[4], boff[4];
    #pragma unroll
    for (int m = 0; m < 4; m++) {
        const int ra = (wr << 6) + (m << 4) + (lane & 15);
        aoff[m] = (ra << 7) + ((((lane >> 4) << 4)) ^ ((ra & 7) << 4));
        const int rb = (wc << 6) + (m << 4) + (lane & 15);
        boff[m] = (rb << 7) + ((((lane >> 4) << 4)) ^ ((rb & 7) << 4));
    }

    f32x4 acc[4][4];
    #pragma unroll
    for (int m = 0; m < 4; m++)
        #pragma unroll
        for (int n = 0; n < 4; n++) acc[m][n] = (f32x4){0.f, 0.f, 0.f, 0.f};

    for (int ks = 0; ks < 16; ks++) {
        if (ks) __syncthreads();
        #pragma unroll
        for (int q = 0; q < 4; q++) {
            GLOAD16(sA[q], Ash + ((wid*4 + q) << 10));
            GLOAD16(sB[q], Bsh + ((wid*4 + q) << 10));
            sA[q] += 32; sB[q] += 32;
        }
        __syncthreads();
        bf16x8 ah[4], al[4], bh[4], bl[4];
        #pragma unroll
        for (int m = 0; m < 4; m++) {
            ah[m] = *(const bf16x8*)(Ash + aoff[m]);
            al[m] = *(const bf16x8*)(Ash + (aoff[m] ^ 64));
            bh[m] = *(const bf16x8*)(Bsh + boff[m]);
            bl[m] = *(const bf16x8*)(Bsh + (boff[m] ^ 64));
        }
        #pragma unroll
        for (int m = 0; m < 4; m++)
            #pragma unroll
            for (int n = 0; n < 4; n++) {
                acc[m][n] = __builtin_amdgcn_mfma_f32_16x16x32_bf16(ah[m], bh[n], acc[m][n], 0, 0, 0);
                acc[m][n] = __builtin_amdgcn_mfma_f32_16x16x32_bf16(ah[m], bl[n], acc[m][n], 0, 0, 0);
                acc[m][n] = __builtin_amdgcn_mfma_f32_16x16x32_bf16(al[m], bh[n], acc[m][n], 0, 0, 0);
            }
    }

    const float gm = gamma[0];
    const int col = lane & 15, rq = lane >> 4;
    #pragma unroll
    for (int m = 0; m < 4; m++)
        #pragma unroll
        for (int r = 0; r < 4; r++) {
            const int i = i0 + (wr << 6) + (m << 4) + (rq << 2) + r;
            const size_t rb = ((size_t)b*512 + i)*Nn;
            #pragma unroll
            for (int n = 0; n < 4; n++) {
                const int nn = n0 + (wc << 6) + (n << 4) + col;
                const float res = bf2f(fTh[rb + nn]) + bf2f(fTl[rb + nn]);
                out[rb + nn] = fmaf(gm, acc[m][n][r], res);
            }
        }
}

// ===========================================================================
// CC attention: energies (norms fused in-block), softmax, apply (split-bf16 x1)
// ===========================================================================
__global__ __launch_bounds__(256) void energy_H(
    const float* __restrict__ q_t, const float* __restrict__ k_t,
    float* __restrict__ att)
{
    __shared__ float Qs[32][129], Ks[32][129];
    __shared__ float pq[32][8], pk[32][8];
    __shared__ float nqs[32], nks[32];
    const int w = blockIdx.x, p = blockIdx.y;
    const int b = p >> 4, pi = (p >> 2) & 3, pj = p & 3;
    const int gw = pj*32 + w;
    const int t = threadIdx.x;
    {
        const int h  = t >> 3;
        const int c0 = (t & 7) * 16;
        const size_t base = ((size_t)b*Nn + (size_t)(pi*32 + h)*Ww + gw) * CQ + c0;
        float sq = 0.f, sk = 0.f;
        #pragma unroll
        for (int u = 0; u < 16; u += 4) {
            float4 qa = *(const float4*)&q_t[base + u];
            float4 ka = *(const float4*)&k_t[base + u];
            Qs[h][c0+u]=qa.x; Qs[h][c0+u+1]=qa.y; Qs[h][c0+u+2]=qa.z; Qs[h][c0+u+3]=qa.w;
            Ks[h][c0+u]=ka.x; Ks[h][c0+u+1]=ka.y; Ks[h][c0+u+2]=ka.z; Ks[h][c0+u+3]=ka.w;
            sq += qa.x*qa.x + qa.y*qa.y + qa.z*qa.z + qa.w*qa.w;
            sk += ka.x*ka.x + ka.y*ka.y + ka.z*ka.z + ka.w*ka.w;
        }
        pq[h][t & 7] = sq; pk[h][t & 7] = sk;
    }
    __syncthreads();
    if (t < 32) {
        float s1 = 0.f, s2 = 0.f;
        #pragma unroll
        for (int j = 0; j < 8; j++) { s1 += pq[t][j]; s2 += pk[t][j]; }
        nqs[t] = sqrtf(s1) + EPSf; nks[t] = sqrtf(s2) + EPSf;
    }
    __syncthreads();
    const int h0 = (t & 15) * 2, g0 = (t >> 4) * 2;
    float a00=0,a01=0,a10=0,a11=0;
    #pragma unroll 4
    for (int c = 0; c < CQ; c++) {
        float q0 = Qs[h0][c], q1 = Qs[h0+1][c];
        float k0 = Ks[g0][c], k1 = Ks[g0+1][c];
        a00 = fmaf(q0,k0,a00); a01 = fmaf(q0,k1,a01);
        a10 = fmaf(q1,k0,a10); a11 = fmaf(q1,k1,a11);
    }
    const size_t ab = (((size_t)p*32 + h0)*32 + w)*64;
    att[ab + g0]            = a00 / (nqs[h0]   * nks[g0]);
    att[ab + g0 + 1]        = a01 / (nqs[h0]   * nks[g0+1]);
    att[ab + 2048 + g0]     = a10 / (nqs[h0+1] * nks[g0]);
    att[ab + 2048 + g0 + 1] = a11 / (nqs[h0+1] * nks[g0+1]);
}

__global__ __launch_bounds__(256) void energy_W(
    const float* __restrict__ q_t, const float* __restrict__ k_t,
    float* __restrict__ att)
{
    __shared__ float Qs[32][129], Ks[32][129];
    __shared__ float pq[32][8], pk[32][8];
    __shared__ float nqs[32], nks[32];
    const int h = blockIdx.x, p = blockIdx.y;
    const int b = p >> 4, pi = (p >> 2) & 3, pj = p & 3;
    const int gh = pi*32 + h;
    const size_t rowpos = (size_t)b*Nn + (size_t)gh*Ww + pj*32;
    const int t = threadIdx.x;
    {
        const int wl = t >> 3;
        const int c0 = (t & 7) * 16;
        const size_t base = (rowpos + wl) * CQ + c0;
        float sq = 0.f, sk = 0.f;
        #pragma unroll
        for (int u = 0; u < 16; u += 4) {
            float4 qa = *(const float4*)&q_t[base + u];
            float4 ka = *(const float4*)&k_t[base + u];
            Qs[wl][c0+u]=qa.x; Qs[wl][c0+u+1]=qa.y; Qs[wl][c0+u+2]=qa.z; Qs[wl][c0+u+3]=qa.w;
            Ks[wl][c0+u]=ka.x; Ks[wl][c0+u+1]=ka.y; Ks[wl][c0+u+2]=ka.z; Ks[wl][c0+u+3]=ka.w;
            sq += qa.x*qa.x + qa.y*qa.y + qa.z*qa.z + qa.w*qa.w;
            sk += ka.x*ka.x + ka.y*ka.y + ka.z*ka.z + ka.w*ka.w;
        }
        pq[wl][t & 7] = sq; pk[wl][t & 7] = sk;
    }
    __syncthreads();
    if (t < 32) {
        float s1 = 0.f, s2 = 0.f;
        #pragma unroll
        for (int j = 0; j < 8; j++) { s1 += pq[t][j]; s2 += pk[t][j]; }
        nqs[t] = sqrtf(s1) + EPSf; nks[t] = sqrtf(s2) + EPSf;
    }
    __syncthreads();
    const int w0 = (t & 15) * 2, g0 = (t >> 4) * 2;
    float a00=0,a01=0,a10=0,a11=0;
    #pragma unroll 4
    for (int c = 0; c < CQ; c++) {
        float q0 = Qs[w0][c], q1 = Qs[w0+1][c];
        float k0 = Ks[g0][c], k1 = Ks[g0+1][c];
        a00 = fmaf(q0,k0,a00); a01 = fmaf(q0,k1,a01);
        a10 = fmaf(q1,k0,a10); a11 = fmaf(q1,k1,a11);
    }
    const size_t ab = (((size_t)p*32 + h)*32 + w0)*64 + 32;
    att[ab + g0]          = a00 / (nqs[w0]   * nks[g0]);
    att[ab + g0 + 1]      = a01 / (nqs[w0]   * nks[g0+1]);
    att[ab + 64 + g0]     = a10 / (nqs[w0+1] * nks[g0]);
    att[ab + 64 + g0 + 1] = a11 / (nqs[w0+1] * nks[g0+1]);
}

__global__ __launch_bounds__(256) void softmax64(float* __restrict__ att)
{
    const size_t idx = (size_t)blockIdx.x * 256 + threadIdx.x;
    float* row = att + idx * 64;
    float v[64];
    float m = -1e30f;
    #pragma unroll
    for (int i = 0; i < 64; i += 4) {
        float4 x4 = *(const float4*)&row[i];
        v[i]=x4.x; v[i+1]=x4.y; v[i+2]=x4.z; v[i+3]=x4.w;
        m = fmaxf(m, fmaxf(fmaxf(x4.x,x4.y), fmaxf(x4.z,x4.w)));
    }
    float s = 0.f;
    #pragma unroll
    for (int i = 0; i < 64; i++) { v[i] = __expf(v[i] - m); s += v[i]; }
    const float inv = 1.f / s;
    #pragma unroll
    for (int i = 0; i < 64; i += 4) {
        float4 x4 = {v[i]*inv, v[i+1]*inv, v[i+2]*inv, v[i+3]*inv};
        *(float4*)&row[i] = x4;
    }
}

// outH: writes x1h/x1l ('=' split write)
__global__ __launch_bounds__(256) void cc_outH(
    const float* __restrict__ v_t, const float* __restrict__ att,
    u16* __restrict__ x1h, u16* __restrict__ x1l)
{
    __shared__ float Vs[32][256];
    __shared__ float At[32][33];
    const int w = blockIdx.x, p = blockIdx.y;
    const int b = p >> 4, pi = (p >> 2) & 3, pj = p & 3;
    const int gw = pj*32 + w;
    const int t = threadIdx.x;
    {
        const int hh = t >> 3, g0 = (t & 7) * 4;
        const float* arow = att + (((size_t)p*32 + hh)*32 + w)*64 + g0;
        float4 a = *(const float4*)arow;
        At[g0][hh]=a.x; At[g0+1][hh]=a.y; At[g0+2][hh]=a.z; At[g0+3][hh]=a.w;
    }
    const int s  = t & 63, hg = t >> 6;
    const int cl = s * 4, h0 = hg * 8;
    for (int half = 0; half < 2; half++) {
        __syncthreads();
        {
            const int g = t >> 3, c0 = (t & 7) * 32;
            const float* src = v_t + ((size_t)b*Nn + (size_t)(pi*32 + g)*Ww + gw)*Cc + half*256 + c0;
            #pragma unroll
            for (int u = 0; u < 32; u += 4)
                *(float4*)&Vs[g][c0+u] = *(const float4*)&src[u];
        }
        __syncthreads();
        float acc[8][4];
        #pragma unroll
        for (int i = 0; i < 8; i++) { acc[i][0]=0.f; acc[i][1]=0.f; acc[i][2]=0.f; acc[i][3]=0.f; }
        #pragma unroll 4
        for (int g = 0; g < 32; g++) {
            const float4 va = *(const float4*)&Vs[g][cl];
            #pragma unroll
            for (int hh = 0; hh < 8; hh++) {
                const float a = At[g][h0+hh];
                acc[hh][0] = fmaf(va.x, a, acc[hh][0]);
                acc[hh][1] = fmaf(va.y, a, acc[hh][1]);
                acc[hh][2] = fmaf(va.z, a, acc[hh][2]);
                acc[hh][3] = fmaf(va.w, a, acc[hh][3]);
            }
        }
        #pragma unroll
        for (int hh = 0; hh < 8; hh++) {
            u16 hs[4] __attribute__((aligned(8)));
            u16 ls[4] __attribute__((aligned(8)));
            #pragma unroll
            for (int j = 0; j < 4; j++) {
                const float v = acc[hh][j];
                const u16 h2 = f2bf(v);
                hs[j] = h2; ls[j] = f2bf(v - bf2f(h2));
            }
            const size_t o = ((size_t)b*Nn + (size_t)(pi*32 + h0+hh)*Ww + gw)*Cc + half*256 + cl;
            *(uint2*)&x1h[o] = *(const uint2*)hs;
            *(uint2*)&x1l[o] = *(const uint2*)ls;
        }
    }
}

// outW: read-modify-write on x1h/x1l (reconstruct, add, re-split)
__global__ __launch_bounds__(256) void cc_outW(
    const float* __restrict__ v_t, const float* __restrict__ att,
    u16* __restrict__ x1h, u16* __restrict__ x1l)
{
    __shared__ float Vs[32][256];
    __shared__ float At[32][33];
    const int h = blockIdx.x, p = blockIdx.y;
    const int b = p >> 4, pi = (p >> 2) & 3, pj = p & 3;
    const int gh = pi*32 + h;
    const size_t rowpos = (size_t)b*Nn + (size_t)gh*Ww + pj*32;
    const int t = threadIdx.x;
    {
        const int wl = t >> 3, g0 = (t & 7) * 4;
        const float* arow = att + (((size_t)p*32 + h)*32 + wl)*64 + 32 + g0;
        float4 a = *(const float4*)arow;
        At[g0][wl]=a.x; At[g0+1][wl]=a.y; At[g0+2][wl]=a.z; At[g0+3][wl]=a.w;
    }
    const int s  = t & 63, wg = t >> 6;
    const int cl = s * 4, w0 = wg * 8;
    for (int half = 0; half < 2; half++) {
        __syncthreads();
        {
            const int g = t >> 3, c0 = (t & 7) * 32;
            const float* src = v_t + (rowpos + g)*Cc + half*256 + c0;
            #pragma unroll
            for (int u = 0; u < 32; u += 4)
                *(float4*)&Vs[g][c0+u] = *(const float4*)&src[u];
        }
        __syncthreads();
        float acc[8][4];
        #pragma unroll
        for (int i = 0; i < 8; i++) { acc[i][0]=0.f; acc[i][1]=0.f; acc[i][2]=0.f; acc[i][3]=0.f; }
        #pragma unroll 4
        for (int g = 0; g < 32; g++) {
            const float4 va = *(const float4*)&Vs[g][cl];
            #pragma unroll
            for (int ww = 0; ww < 8; ww++) {
                const float a = At[g][w0+ww];
                acc[ww][0] = fmaf(va.x, a, acc[ww][0]);
                acc[ww][1] = fmaf(va.y, a, acc[ww][1]);
                acc[ww][2] = fmaf(va.z, a, acc[ww][2]);
                acc[ww][3] = fmaf(va.w, a, acc[ww][3]);
            }
        }
        #pragma unroll
        for (int ww = 0; ww < 8; ww++) {
            const size_t o = (rowpos + w0+ww)*Cc + half*256 + cl;
            const uint2 ph = *(const uint2*)&x1h[o];
            const uint2 pl = *(const uint2*)&x1l[o];
            float v[4];
            v[0] = bf2f((u16)ph.x)        + bf2f((u16)pl.x)        + acc[ww][0];
            v[1] = bf2f((u16)(ph.x>>16))  + bf2f((u16)(pl.x>>16))  + acc[ww][1];
            v[2] = bf2f((u16)ph.y)        + bf2f((u16)pl.y)        + acc[ww][2];
            v[3] = bf2f((u16)(ph.y>>16))  + bf2f((u16)(pl.y>>16))  + acc[ww][3];
            u16 hs[4] __attribute__((aligned(8)));
            u16 ls[4] __attribute__((aligned(8)));
            #pragma unroll
            for (int j = 0; j < 4; j++) {
                const u16 h2 = f2bf(v[j]);
                hs[j] = h2; ls[j] = f2bf(v[j] - bf2f(h2));
            }
            *(uint2*)&x1h[o] = *(const uint2*)hs;
            *(uint2*)&x1l[o] = *(const uint2*)ls;
        }
    }
}

// ===========================================================================
// CAM small kernels
// ===========================================================================
// block-per-channel norm² from fT rows (contiguous) — no atomics
__global__ __launch_bounds__(256) void cam_normacc(
    const u16* __restrict__ fTh, const u16* __restrict__ fTl, float* __restrict__ nf2)
{
    const int bc = blockIdx.x;             // b*512 + ch
    const u16* ph = fTh + (size_t)bc * Nn;
    const u16* pl = fTl + (size_t)bc * Nn;
    const int t = threadIdx.x;
    float s = 0.f;
    #pragma unroll
    for (int base = 0; base < Nn; base += 2048) {
        const int i = base + t*8;
        const uint4 hv = *(const uint4*)&ph[i];
        const uint4 lv = *(const uint4*)&pl[i];
        const u32 hw[4] = {hv.x, hv.y, hv.z, hv.w};
        const u32 lw[4] = {lv.x, lv.y, lv.z, lv.w};
        #pragma unroll
        for (int j = 0; j < 4; j++) {
            const float a  = bf2f((u16)hw[j])       + bf2f((u16)lw[j]);
            const float b2 = bf2f((u16)(hw[j]>>16)) + bf2f((u16)(lw[j]>>16));
            s = fmaf(a, a, s); s = fmaf(b2, b2, s);
        }
    }
    #pragma unroll
    for (int o = 32; o > 0; o >>= 1) s += __shfl_xor(s, o, 64);
    __shared__ float red[4];
    if ((t & 63) == 0) red[t >> 6] = s;
    __syncthreads();
    if (t == 0) nf2[bc] = red[0] + red[1] + red[2] + red[3];
}

__global__ __launch_bounds__(256) void cam_softmax(
    const float* __restrict__ Gp, const float* __restrict__ nf2,
    float* __restrict__ P)
{
    const int b = blockIdx.x >> 9, i = blockIdx.x & 511;
    const int t = threadIdx.x;
    __shared__ float red[8];
    const size_t roff = ((size_t)b*512 + i) * 512;
    float v0 = 0.f, v1 = 0.f;
    #pragma unroll
    for (int kc = 0; kc < 8; kc++) {
        const float* gp = Gp + (size_t)(kc*4 + b)*512*512 + (size_t)i*512;
        v0 += gp[t];
        v1 += gp[t + 256];
    }
    const float nfi = sqrtf(nf2[b*512 + i]) + EPSf;
    const float nj0 = sqrtf(nf2[b*512 + t]) + EPSf;
    const float nj1 = sqrtf(nf2[b*512 + t + 256]) + EPSf;
    float e0 = v0 / (nfi*nj0), e1 = v1 / (nfi*nj1);
    float m = fmaxf(e0, e1);
    #pragma unroll
    for (int o = 32; o > 0; o >>= 1) m = fmaxf(m, __shfl_xor(m, o, 64));
    if ((t & 63) == 0) red[t >> 6] = m;
    __syncthreads();
    m = fmaxf(fmaxf(red[0], red[1]), fmaxf(red[2], red[3]));
    float p0 = __expf(e0 - m), p1 = __expf(e1 - m);
    float s = p0 + p1;
    #pragma unroll
    for (int o = 32; o > 0; o >>= 1) s += __shfl_xor(s, o, 64);
    if ((t & 63) == 0) red[4 + (t >> 6)] = s;
    __syncthreads();
    s = red[4] + red[5] + red[6] + red[7];
    const float inv = 1.f / s;
    P[roff + t]       = p0 * inv;
    P[roff + t + 256] = p1 * inv;
}

// ===========================================================================
extern "C" void kernel_launch(void* const* d_in, const int* in_sizes, int n_in,
                              void* d_out, int out_size, void* d_ws, size_t ws_size,
                              hipStream_t stream)
{
    (void)in_sizes; (void)n_in; (void)out_size; (void)ws_size;
    const float* x    = (const float*)d_in[0];
    const float* wqp  = (const float*)d_in[1];
    const float* bqp  = (const float*)d_in[2];
    const float* wkp  = (const float*)d_in[3];
    const float* bkp  = (const float*)d_in[4];
    const float* wvp  = (const float*)d_in[5];
    const float* bvp  = (const float*)d_in[6];
    const float* gmp  = (const float*)d_in[7];
    float* out = (float*)d_out;

    char* W = (char*)d_ws;
    float* q_t = (float*)(W);                    //  33,554,432 B
    float* k_t = (float*)(W + 33554432);         //  33,554,432
    float* v_t = (float*)(W + 67108864);         // 134,217,728
    u16*   x1h = (u16*)  (W + 201326592);        //  67,108,864
    u16*   x1l = (u16*)  (W + 268435456);        //  67,108,864
    float* att = (float*)(W + 335544320);        //  16,777,216
    u16*   xh  = (u16*)  (W + 352321536);        //  67,108,864
    u16*   xl  = (u16*)  (W + 419430400);        //  67,108,864
    u16*   wh  = (u16*)  (W + 486539264);        //     786,432
    u16*   wl  = (u16*)  (W + 487325696);        //     786,432
    float* bcat= (float*)(W + 488112128);        //       3,072  (end ~488 MB)
    // CAM scratch aliases dead q_t/k_t region (67 MB):
    float* nf2 = (float*)(W);                                    //   8 KB
    float* Gp  = (float*)(W + 16384);                            //  32 MB
    float* P   = (float*)(W + 16384 + 33554432);                 //   4 MB
    u16*   Ph  = (u16*)  (W + 16384 + 33554432 + 4194304);       //   2 MB
    u16*   Pl  = (u16*)  (W + 16384 + 33554432 + 4194304 + 2097152);
    // fT aliases v_t (dead after iteration-2 cc_out):
    u16*   fTh = (u16*)(W + 67108864);                           //  67 MB
    u16*   fTl = (u16*)(W + 134217728);                          //  67 MB

    conv_w  <<<dim3(768),      256, 0, stream>>>(wqp,bqp, wkp,bkp, wvp,bvp, wh, wl, bcat);
    conv_x_t<<<dim3(256,8,4),  256, 0, stream>>>(x, xh, xl);

    for (int it = 0; it < 2; it++) {
        const u16* ah = (it == 0) ? xh : x1h;
        const u16* al = (it == 0) ? xl : x1l;
        qkv_mfma <<<dim3(128,6,4), 256, 0, stream>>>(ah, al, wh, wl, bcat, q_t, k_t, v_t);
        energy_H <<<dim3(32,64),   256, 0, stream>>>(q_t, k_t, att);
        energy_W <<<dim3(32,64),   256, 0, stream>>>(q_t, k_t, att);
        softmax64<<<dim3(256),     256, 0, stream>>>(att);
        cc_outH  <<<dim3(32,64),   256, 0, stream>>>(v_t, att, x1h, x1l);
        cc_outW  <<<dim3(32,64),   256, 0, stream>>>(v_t, att, x1h, x1l);
    }

    // CAM
    conv_t_cl  <<<dim3(256,8,4), 256, 0, stream>>>(x1h, x1l, fTh, fTl);
    cam_normacc<<<dim3(2048),    256, 0, stream>>>(fTh, fTl, nf2);
    gram_mfma  <<<dim3(320),     256, 0, stream>>>(fTh, fTl, Gp);
    cam_softmax<<<dim3(2048),    256, 0, stream>>>(Gp, nf2, P);
    conv_cl    <<<dim3(512),     256, 0, stream>>>(P, Ph, Pl, (long)Bn*512*512);
    camout_mfma<<<dim3(128,4,4), 256, 0, stream>>>(Ph, Pl, x1h, x1l, fTh, fTl, gmp, out);
}